// Round 2
// baseline (253.433 us; speedup 1.0000x reference)
//
#include <hip/hip_runtime.h>
#include <math.h>

#define NB 64
#define NGRAPH 2000
#define EGRAPH 64000
#define NN (NB*NGRAPH)      // 128000
#define NE (NB*EGRAPH)      // 4096000
#define KSEL 1600
#define FEAT 10000
#define EMBD 64
#define G1D 32
#define G2D 32
#define DENSED 64
#define NCLSD 10
#define NCHUNK 8
#define CHUNK_E (EGRAPH/NCHUNK)   // 8000
#define NQD 8                     // dst-ranges per graph (scatter)
#define QNODES (NGRAPH/NQD)       // 250
#define LOUT_CAP 10000            // staging cap (avg 8000, +24 sigma)

// R16: agg kernels are L2-latency-bound (R15 post-mortem: VALU 28%, DS
// removal bought only 2.5us, HBM 8%). Deepen gather pipeline 2->4:
// 16 edges per while-iter, 4 float4 + 4 csr loads in flight per lane,
// serial dependent iterations per node halve (avg deg 32: 4 -> 2).
// csr[] holds GLOBAL row byte offsets (src*128), padded by 16 ints.
// Graph->XCD ownership: graph g lives on XCD (g>>3).

// ---------------------------------------------------------------------------
// K1: prep = per-chunk LDS histogram of dst (blocks 0..511)
//          + embW = emb @ W1 (blocks 512..1761). 256 threads.
// ---------------------------------------------------------------------------
__global__ __launch_bounds__(256) void prep_kernel(const int* __restrict__ ei,
                                                   int* __restrict__ chist,
                                                   const float* __restrict__ emb,
                                                   const float* __restrict__ W1,
                                                   float* __restrict__ embW)
{
    __shared__ float shmem[2048];        // 8 KB union: hist[2000] / W1s[2048]
    const int tid = threadIdx.x;
    if (blockIdx.x < 512) {
        int* hist = (int*)shmem;
        const int lb = blockIdx.x;           // 512 blocks
        const int xcd = lb & 7, t = lb >> 3; // t in [0,64)
        const int g = xcd * 8 + (t >> 3);
        const int q = t & 7;
        const int base_e = g * EGRAPH + q * CHUNK_E;
        const int base_n = g * NGRAPH;
        for (int v = tid; v < NGRAPH; v += 256) hist[v] = 0;
        __syncthreads();
        for (int k = tid; k < CHUNK_E; k += 256) {
            int d = ei[NE + base_e + k];
            atomicAdd(&hist[d - base_n], 1);      // LDS atomic
        }
        __syncthreads();
        int* out = chist + (size_t)(g * NCHUNK + q) * NGRAPH;
        for (int v = tid; v < NGRAPH; v += 256) out[v] = hist[v];
    } else {
        float* W1s = shmem;
        for (int i = tid; i < EMBD * G1D; i += 256) W1s[i] = W1[i];
        __syncthreads();
        int id = (blockIdx.x - 512) * 256 + tid;
        int r = id >> 5, c = id & 31;
        if (r >= FEAT) return;
        const float* er = emb + r * EMBD;
        float acc = 0.f;
        #pragma unroll 8
        for (int k = 0; k < EMBD; ++k) acc += er[k] * W1s[k * G1D + c];
        embW[r * G1D + c] = acc;
    }
}

// ---------------------------------------------------------------------------
// K2: per-graph: deg = sum of 8 chunk hists -> dinv; exclusive scan ->
//      row_start. one block per graph.
// ---------------------------------------------------------------------------
__global__ __launch_bounds__(256) void scan_graph(const int* __restrict__ chist,
                                                  float* __restrict__ dinv,
                                                  int* __restrict__ row_start)
{
    __shared__ int hist[NGRAPH];
    __shared__ int csA[256];
    __shared__ int csB[256];
    const int b = (blockIdx.x & 7) * 8 + (blockIdx.x >> 3);   // XCD-local graph
    const int tid = threadIdx.x;
    const int base_n = b * NGRAPH, base_e = b * EGRAPH;
    const int* ch = chist + (size_t)b * NCHUNK * NGRAPH;

    for (int v = tid; v < NGRAPH; v += 256) {
        int tot = 0;
        #pragma unroll
        for (int q = 0; q < NCHUNK; ++q) tot += ch[q * NGRAPH + v];
        hist[v] = tot;
        dinv[base_n + v] = rsqrtf((float)(tot + 1));   // +1 self-loop
    }
    __syncthreads();
    if (tid < 250) {
        int s = 0;
        #pragma unroll
        for (int i = 0; i < 8; ++i) s += hist[tid * 8 + i];
        csA[tid] = s;
    }
    __syncthreads();
    int* sb = csA; int* db = csB;
    for (int off = 1; off < 256; off <<= 1) {
        int v = 0;
        if (tid < 250) { v = sb[tid]; if (tid >= off) v += sb[tid - off]; }
        if (tid < 250) db[tid] = v;
        __syncthreads();
        int* t = sb; sb = db; db = t;
    }
    if (tid < 250) {
        int run = (tid == 0) ? 0 : sb[tid - 1];
        #pragma unroll
        for (int i = 0; i < 8; ++i) {
            int idx = tid * 8 + i;
            int c = hist[idx];
            row_start[base_n + idx] = base_e + run;
            run += c;
        }
    }
}

// ---------------------------------------------------------------------------
// K3: mid = dst-range scatter with LDS staging (blocks 0..511)
//         + A' gather (blocks 512..1511). 1024 threads.
// scatter stores GLOBAL byte offset src*128.
// ---------------------------------------------------------------------------
__global__ __launch_bounds__(1024) void mid_kernel(const int* __restrict__ ei,
                                                   const int* __restrict__ row_start,
                                                   int* __restrict__ csr,
                                                   const int* __restrict__ x,
                                                   const float* __restrict__ embW,
                                                   const float* __restrict__ dinv,
                                                   float* __restrict__ A)
{
    __shared__ int cur[QNODES];
    __shared__ int lout[LOUT_CAP];
    const int tid = threadIdx.x;
    if (blockIdx.x < 512) {
        const int lb = blockIdx.x;             // 512 blocks
        const int xcd = lb & 7, t = lb >> 3;   // t in [0,64)
        const int g = xcd * 8 + (t >> 3);
        const int qd = t & 7;
        const int base_n = g * NGRAPH;
        const int lo = qd * QNODES;
        const int base = row_start[base_n + lo];
        const int qend = (g == NB - 1 && qd == NQD - 1) ? NE
                         : row_start[base_n + lo + QNODES];
        for (int v = tid; v < QNODES; v += 1024)
            cur[v] = row_start[base_n + lo + v] - base;
        __syncthreads();
        const int4* srcp = (const int4*)(ei + g * EGRAPH);
        const int4* dstp = (const int4*)(ei + NE + g * EGRAPH);
        const int sub = base_n + lo;
        for (int k = tid; k < EGRAPH / 4; k += 1024) {
            int4 d4 = dstp[k];
            int4 s4 = srcp[k];
            int d, pos;
            d = d4.x - sub;
            if ((unsigned)d < (unsigned)QNODES) {
                pos = atomicAdd(&cur[d], 1);
                if (pos < LOUT_CAP) lout[pos] = s4.x << 7;
            }
            d = d4.y - sub;
            if ((unsigned)d < (unsigned)QNODES) {
                pos = atomicAdd(&cur[d], 1);
                if (pos < LOUT_CAP) lout[pos] = s4.y << 7;
            }
            d = d4.z - sub;
            if ((unsigned)d < (unsigned)QNODES) {
                pos = atomicAdd(&cur[d], 1);
                if (pos < LOUT_CAP) lout[pos] = s4.z << 7;
            }
            d = d4.w - sub;
            if ((unsigned)d < (unsigned)QNODES) {
                pos = atomicAdd(&cur[d], 1);
                if (pos < LOUT_CAP) lout[pos] = s4.w << 7;
            }
        }
        __syncthreads();
        int size = qend - base;
        if (size > LOUT_CAP) size = LOUT_CAP;   // safety clamp
        for (int i = tid; i < size; i += 1024)
            csr[base + i] = lout[i];
    } else {
        int id = (blockIdx.x - 512) * 1024 + tid;   // id = v*8 + r
        int v = id >> 3, r = id & 7;
        int xv = x[v];
        float dv = dinv[v];
        float4 e = ((const float4*)(embW + (size_t)xv * G1D))[r];
        e.x *= dv; e.y *= dv; e.z *= dv; e.w *= dv;
        ((float4*)(A + (size_t)v * G1D))[r] = e;
    }
}

// ---------------------------------------------------------------------------
// agg: half-wave (32 lanes) per node, 4 edge-slots x 8 lanes x float4,
// R16: 4-deep pipeline (16 edges/iter, 4 gathers in flight per lane)
// + rolling next-node prefetch. csr entries are pre-shifted global byte
// offsets; csr padded 16 ints (max read re+slot+12 <= NE+15).
// ---------------------------------------------------------------------------

// K4: layer-1 aggregation + ReLU + (h1 @ W2) * dinv -> B'
__global__ __launch_bounds__(256) void agg1_kernel(const float* __restrict__ Ain,
                                                   const float* __restrict__ dinv,
                                                   const int* __restrict__ row_start,
                                                   const int* __restrict__ csr,
                                                   const float* __restrict__ b1,
                                                   const float* __restrict__ W2,
                                                   float* __restrict__ Bout)
{
    __shared__ float hsh[8][G2D];           // per half-wave h row (1 KB)
    const int lb = blockIdx.x;
    const int xcd = lb & 7, idx = lb >> 3;
    const int b = xcd * 8 + (idx >> 5);     // graph
    const int blk = idx & 31;
    const int half = threadIdx.x >> 5;      // 0..7
    const int hl = threadIdx.x & 31;        // lane in half-wave
    const int slot = hl >> 3;               // 0..3 edge slot
    const int r = hl & 7;                   // column quad: cols 4r..4r+3
    const int roff = r << 4;                // byte offset within row
    const char* Abase = (const char*)Ain;
    const int base_n = b * NGRAPH;
    const float4 bias4 = ((const float4*)b1)[r];

    // this lane's W2 column (compiler may keep in regs or re-load via L1)
    float w2c[G1D];
    #pragma unroll
    for (int k = 0; k < G1D; ++k) w2c[k] = W2[k * G2D + hl];

    const int vloc0 = blk * 64 + half * 8;
    int v = base_n + ((vloc0 < NGRAPH) ? vloc0 : NGRAPH - 1);
    int rs = row_start[v];
    int re = (v == NN - 1) ? NE : row_start[v + 1];
    int s0 = csr[rs + slot];
    int s1 = csr[rs + slot + 4];
    int s2 = csr[rs + slot + 8];
    int s3 = csr[rs + slot + 12];

    for (int i = 0; i < 8; ++i) {
        int vloc = vloc0 + i;
        if (vloc >= NGRAPH) break;
        int re_next = (v + 1 >= NN - 1) ? NE : row_start[v + 2];
        int n0 = csr[re + slot];
        int n1 = csr[re + slot + 4];
        int n2 = csr[re + slot + 8];
        int n3 = csr[re + slot + 12];

        int me = rs + ((re - rs) & ~15);    // 16-aligned unpredicated region
        float4 acc0 = make_float4(0.f, 0.f, 0.f, 0.f);
        float4 acc1 = make_float4(0.f, 0.f, 0.f, 0.f);
        float4 acc2 = make_float4(0.f, 0.f, 0.f, 0.f);
        float4 acc3 = make_float4(0.f, 0.f, 0.f, 0.f);
        if (slot == 0)
            acc0 = ((const float4*)(Ain + (size_t)v * G1D))[r];   // self-loop
        int j = rs + slot;
        while (j < me) {
            int jn = j + 16;
            int t0 = csr[jn];               // unguarded 16-ahead (csr padded)
            int t1 = csr[jn + 4];
            int t2 = csr[jn + 8];
            int t3 = csr[jn + 12];
            float4 a0 = *(const float4*)(Abase + (unsigned)(s0 + roff));
            float4 a1 = *(const float4*)(Abase + (unsigned)(s1 + roff));
            float4 a2 = *(const float4*)(Abase + (unsigned)(s2 + roff));
            float4 a3 = *(const float4*)(Abase + (unsigned)(s3 + roff));
            acc0.x += a0.x; acc0.y += a0.y; acc0.z += a0.z; acc0.w += a0.w;
            acc1.x += a1.x; acc1.y += a1.y; acc1.z += a1.z; acc1.w += a1.w;
            acc2.x += a2.x; acc2.y += a2.y; acc2.z += a2.z; acc2.w += a2.w;
            acc3.x += a3.x; acc3.y += a3.y; acc3.z += a3.z; acc3.w += a3.w;
            j = jn; s0 = t0; s1 = t1; s2 = t2; s3 = t3;
        }
        {   // tail: rem = re - me in [0,16); slot covers positions slot+4m
            int jt = me + slot;
            if (jt < re) {
                float4 a = *(const float4*)(Abase + (unsigned)(s0 + roff));
                acc0.x += a.x; acc0.y += a.y; acc0.z += a.z; acc0.w += a.w;
            }
            if (jt + 4 < re) {
                float4 a = *(const float4*)(Abase + (unsigned)(s1 + roff));
                acc1.x += a.x; acc1.y += a.y; acc1.z += a.z; acc1.w += a.w;
            }
            if (jt + 8 < re) {
                float4 a = *(const float4*)(Abase + (unsigned)(s2 + roff));
                acc2.x += a.x; acc2.y += a.y; acc2.z += a.z; acc2.w += a.w;
            }
            if (jt + 12 < re) {
                float4 a = *(const float4*)(Abase + (unsigned)(s3 + roff));
                acc3.x += a.x; acc3.y += a.y; acc3.z += a.z; acc3.w += a.w;
            }
        }
        float4 acc;
        acc.x = (acc0.x + acc1.x) + (acc2.x + acc3.x);
        acc.y = (acc0.y + acc1.y) + (acc2.y + acc3.y);
        acc.z = (acc0.z + acc1.z) + (acc2.z + acc3.z);
        acc.w = (acc0.w + acc1.w) + (acc2.w + acc3.w);
        #pragma unroll
        for (int off = 8; off <= 16; off <<= 1) {
            acc.x += __shfl_xor(acc.x, off, 32);
            acc.y += __shfl_xor(acc.y, off, 32);
            acc.z += __shfl_xor(acc.z, off, 32);
            acc.w += __shfl_xor(acc.w, off, 32);
        }
        float dv = dinv[v];
        if (slot == 0) {
            float4 h4;
            h4.x = fmaxf(dv * acc.x + bias4.x, 0.f);
            h4.y = fmaxf(dv * acc.y + bias4.y, 0.f);
            h4.z = fmaxf(dv * acc.z + bias4.z, 0.f);
            h4.w = fmaxf(dv * acc.w + bias4.w, 0.f);
            ((float4*)&hsh[half][0])[r] = h4;      // ds_write_b128
        }
        // same-wave in-order LDS: reads below see the write after lgkmcnt
        float o0 = 0.f, o1 = 0.f, o2 = 0.f, o3 = 0.f;
        const float4* hrow = (const float4*)&hsh[half][0];
        #pragma unroll
        for (int q = 0; q < 8; ++q) {              // 8 broadcast ds_read_b128
            float4 hh = hrow[q];
            o0 += hh.x * w2c[4 * q + 0];
            o1 += hh.y * w2c[4 * q + 1];
            o2 += hh.z * w2c[4 * q + 2];
            o3 += hh.w * w2c[4 * q + 3];
        }
        Bout[(size_t)v * G2D + hl] = dv * ((o0 + o1) + (o2 + o3));
        v = v + 1;
        rs = re; re = re_next; s0 = n0; s1 = n1; s2 = n2; s3 = n3;
    }
}

// K5: layer-2 aggregation + ReLU -> h2 ; score = tanh(h2 . pw / ||pw||)
__global__ __launch_bounds__(256) void agg2_kernel(const float* __restrict__ Bin,
                                                   const float* __restrict__ dinv,
                                                   const int* __restrict__ row_start,
                                                   const int* __restrict__ csr,
                                                   const float* __restrict__ b2,
                                                   const float* __restrict__ pool_w,
                                                   float* __restrict__ h2out,
                                                   float* __restrict__ scores)
{
    const int lb = blockIdx.x;
    const int xcd = lb & 7, idx = lb >> 3;
    const int b = xcd * 8 + (idx >> 5);
    const int blk = idx & 31;
    const int half = threadIdx.x >> 5;
    const int hl = threadIdx.x & 31;
    const int slot = hl >> 3;
    const int r = hl & 7;
    const int roff = r << 4;
    const char* Bbase = (const char*)Bin;
    const int base_n = b * NGRAPH;
    const float4 bias4 = ((const float4*)b2)[r];
    const float4 pw4 = ((const float4*)pool_w)[r];

    float pw = pool_w[hl];
    float nsq = pw * pw;
    #pragma unroll
    for (int off = 16; off; off >>= 1) nsq += __shfl_xor(nsq, off, 32);
    const float inv_norm = rsqrtf(nsq);

    const int vloc0 = blk * 64 + half * 8;
    int v = base_n + ((vloc0 < NGRAPH) ? vloc0 : NGRAPH - 1);
    int rs = row_start[v];
    int re = (v == NN - 1) ? NE : row_start[v + 1];
    int s0 = csr[rs + slot];
    int s1 = csr[rs + slot + 4];
    int s2 = csr[rs + slot + 8];
    int s3 = csr[rs + slot + 12];

    for (int i = 0; i < 8; ++i) {
        int vloc = vloc0 + i;
        if (vloc >= NGRAPH) break;
        int re_next = (v + 1 >= NN - 1) ? NE : row_start[v + 2];
        int n0 = csr[re + slot];
        int n1 = csr[re + slot + 4];
        int n2 = csr[re + slot + 8];
        int n3 = csr[re + slot + 12];

        int me = rs + ((re - rs) & ~15);
        float4 acc0 = make_float4(0.f, 0.f, 0.f, 0.f);
        float4 acc1 = make_float4(0.f, 0.f, 0.f, 0.f);
        float4 acc2 = make_float4(0.f, 0.f, 0.f, 0.f);
        float4 acc3 = make_float4(0.f, 0.f, 0.f, 0.f);
        if (slot == 0)
            acc0 = ((const float4*)(Bin + (size_t)v * G2D))[r];
        int j = rs + slot;
        while (j < me) {
            int jn = j + 16;
            int t0 = csr[jn];
            int t1 = csr[jn + 4];
            int t2 = csr[jn + 8];
            int t3 = csr[jn + 12];
            float4 a0 = *(const float4*)(Bbase + (unsigned)(s0 + roff));
            float4 a1 = *(const float4*)(Bbase + (unsigned)(s1 + roff));
            float4 a2 = *(const float4*)(Bbase + (unsigned)(s2 + roff));
            float4 a3 = *(const float4*)(Bbase + (unsigned)(s3 + roff));
            acc0.x += a0.x; acc0.y += a0.y; acc0.z += a0.z; acc0.w += a0.w;
            acc1.x += a1.x; acc1.y += a1.y; acc1.z += a1.z; acc1.w += a1.w;
            acc2.x += a2.x; acc2.y += a2.y; acc2.z += a2.z; acc2.w += a2.w;
            acc3.x += a3.x; acc3.y += a3.y; acc3.z += a3.z; acc3.w += a3.w;
            j = jn; s0 = t0; s1 = t1; s2 = t2; s3 = t3;
        }
        {
            int jt = me + slot;
            if (jt < re) {
                float4 a = *(const float4*)(Bbase + (unsigned)(s0 + roff));
                acc0.x += a.x; acc0.y += a.y; acc0.z += a.z; acc0.w += a.w;
            }
            if (jt + 4 < re) {
                float4 a = *(const float4*)(Bbase + (unsigned)(s1 + roff));
                acc1.x += a.x; acc1.y += a.y; acc1.z += a.z; acc1.w += a.w;
            }
            if (jt + 8 < re) {
                float4 a = *(const float4*)(Bbase + (unsigned)(s2 + roff));
                acc2.x += a.x; acc2.y += a.y; acc2.z += a.z; acc2.w += a.w;
            }
            if (jt + 12 < re) {
                float4 a = *(const float4*)(Bbase + (unsigned)(s3 + roff));
                acc3.x += a.x; acc3.y += a.y; acc3.z += a.z; acc3.w += a.w;
            }
        }
        float4 acc;
        acc.x = (acc0.x + acc1.x) + (acc2.x + acc3.x);
        acc.y = (acc0.y + acc1.y) + (acc2.y + acc3.y);
        acc.z = (acc0.z + acc1.z) + (acc2.z + acc3.z);
        acc.w = (acc0.w + acc1.w) + (acc2.w + acc3.w);
        #pragma unroll
        for (int off = 8; off <= 16; off <<= 1) {
            acc.x += __shfl_xor(acc.x, off, 32);
            acc.y += __shfl_xor(acc.y, off, 32);
            acc.z += __shfl_xor(acc.z, off, 32);
            acc.w += __shfl_xor(acc.w, off, 32);
        }
        float dv = dinv[v];
        float4 h4;
        h4.x = fmaxf(dv * acc.x + bias4.x, 0.f);
        h4.y = fmaxf(dv * acc.y + bias4.y, 0.f);
        h4.z = fmaxf(dv * acc.z + bias4.z, 0.f);
        h4.w = fmaxf(dv * acc.w + bias4.w, 0.f);
        if (slot == 0)
            ((float4*)(h2out + (size_t)v * G2D))[r] = h4;
        float t = h4.x * pw4.x + h4.y * pw4.y + h4.z * pw4.z + h4.w * pw4.w;
        t += __shfl_xor(t, 1, 32);
        t += __shfl_xor(t, 2, 32);
        t += __shfl_xor(t, 4, 32);
        if (hl == 0) scores[v] = tanhf(t * inv_norm);
        v = v + 1;
        rs = re; re = re_next; s0 = n0; s1 = n1; s2 = n2; s3 = n3;
    }
}

// ---------------------------------------------------------------------------
// K6: per-graph top-K(1600 of 2000) via 4-pass radix-256 select + parallel
// scaled max-pool + dense MLP. one block per graph, 256 threads.
// ---------------------------------------------------------------------------
__global__ __launch_bounds__(256) void topk_pool_mlp(const float* __restrict__ h2,
                                                     const float* __restrict__ scores,
                                                     const float* __restrict__ dense_W,
                                                     const float* __restrict__ dense_b,
                                                     const float* __restrict__ out_W,
                                                     const float* __restrict__ out_b,
                                                     float* __restrict__ out)
{
    __shared__ unsigned keys[NGRAPH];
    __shared__ float    sval[NGRAPH];
    __shared__ unsigned char inc[NGRAPH];
    __shared__ int  hist[256];
    __shared__ int  csA[256];
    __shared__ int  csB[256];
    __shared__ int  sel[2];
    __shared__ int  redc[4];
    __shared__ float redf[32][32];
    __shared__ float gvec[32];
    __shared__ float dvec[DENSED];
    const int b = (blockIdx.x & 7) * 8 + (blockIdx.x >> 3);   // XCD-local graph
    const int tid = threadIdx.x;
    const int base_n = b * NGRAPH;

    for (int v = tid; v < NGRAPH; v += 256) {
        float f = scores[base_n + v];
        sval[v] = f;
        unsigned u = __float_as_uint(f);
        keys[v] = (u & 0x80000000u) ? ~u : (u | 0x80000000u);  // monotone map
    }
    __syncthreads();

    unsigned T = 0;
    int need = KSEL;
    #pragma unroll
    for (int pass = 0; pass < 4; ++pass) {
        const int s = 24 - pass * 8;
        const unsigned hi_mask = (pass == 0) ? 0u : (0xFFFFFFFFu << (s + 8));
        hist[tid] = 0;
        __syncthreads();
        for (int v = tid; v < NGRAPH; v += 256) {
            unsigned k = keys[v];
            if ((k & hi_mask) == (T & hi_mask))
                atomicAdd(&hist[(k >> s) & 255], 1);
        }
        __syncthreads();
        csA[tid] = hist[255 - tid];
        __syncthreads();
        int* sb = csA; int* db = csB;
        for (int off = 1; off < 256; off <<= 1) {
            int val = sb[tid];
            if (tid >= off) val += sb[tid - off];
            db[tid] = val;
            __syncthreads();
            int* t = sb; sb = db; db = t;
        }
        {
            const int d = tid;
            int suf_d = sb[255 - d];
            int suf_d1 = (d == 255) ? 0 : sb[254 - d];
            if (suf_d >= need && suf_d1 < need) {
                sel[0] = d;
                sel[1] = suf_d1;
            }
        }
        __syncthreads();
        T |= ((unsigned)sel[0]) << s;
        need -= sel[1];
        __syncthreads();
    }

    const int wid = tid >> 6, ln = tid & 63;
    int cg = 0, ce = 0;
    for (int v = tid; v < NGRAPH; v += 256) {
        cg += (keys[v] > T) ? 1 : 0;
        ce += (keys[v] == T) ? 1 : 0;
    }
    int packed = (cg << 16) | ce;
    #pragma unroll
    for (int off = 32; off; off >>= 1) packed += __shfl_down(packed, off, 64);
    if (ln == 0) redc[wid] = packed;
    __syncthreads();
    int tot = redc[0] + redc[1] + redc[2] + redc[3];
    int m_gt = tot >> 16, m_eq = tot & 0xffff;
    int needed = KSEL - m_gt;
    float fT = (T & 0x80000000u) ? __uint_as_float(T & 0x7fffffffu)
                                 : __uint_as_float(~T);
    if (m_eq == needed || fT == 0.0f) {
        for (int v = tid; v < NGRAPH; v += 256) inc[v] = (keys[v] >= T) ? 1 : 0;
    } else {
        if (tid == 0) {
            int take = 0;
            for (int v = 0; v < NGRAPH; ++v) {
                unsigned k = keys[v];
                if (k > T) inc[v] = 1;
                else if (k == T && take < needed) { inc[v] = 1; ++take; }
                else inc[v] = 0;
            }
        }
    }
    __syncthreads();

    {
        const int rowslot = tid >> 3;
        const int c4 = tid & 7;
        float4 m4 = make_float4(-INFINITY, -INFINITY, -INFINITY, -INFINITY);
        for (int v = rowslot; v < NGRAPH; v += 32) {
            float4 hrow = ((const float4*)(h2 + (size_t)(base_n + v) * G2D))[c4];
            float sv = inc[v] ? sval[v] : 0.f;
            float big = inc[v] ? 0.f : -INFINITY;
            m4.x = fmaxf(m4.x, sv * hrow.x + big);
            m4.y = fmaxf(m4.y, sv * hrow.y + big);
            m4.z = fmaxf(m4.z, sv * hrow.z + big);
            m4.w = fmaxf(m4.w, sv * hrow.w + big);
        }
        redf[rowslot][c4 * 4 + 0] = m4.x;
        redf[rowslot][c4 * 4 + 1] = m4.y;
        redf[rowslot][c4 * 4 + 2] = m4.z;
        redf[rowslot][c4 * 4 + 3] = m4.w;
    }
    __syncthreads();
    if (tid < 32) {
        float g = redf[0][tid];
        #pragma unroll
        for (int rr = 1; rr < 32; ++rr) g = fmaxf(g, redf[rr][tid]);
        gvec[tid] = g;
    }
    __syncthreads();
    if (tid < DENSED) {
        float t = dense_b[tid];
        #pragma unroll
        for (int k = 0; k < G2D; ++k) t += gvec[k] * dense_W[k * DENSED + tid];
        dvec[tid] = fmaxf(t, 0.f);
    }
    __syncthreads();
    if (tid < NCLSD) {
        float o = out_b[tid];
        #pragma unroll
        for (int j = 0; j < DENSED; ++j) o += dvec[j] * out_W[j * NCLSD + tid];
        out[b * NCLSD + tid] = o;
    }
}

// ---------------------------------------------------------------------------
extern "C" void kernel_launch(void* const* d_in, const int* in_sizes, int n_in,
                              void* d_out, int out_size, void* d_ws, size_t ws_size,
                              hipStream_t stream)
{
    (void)in_sizes; (void)n_in; (void)out_size; (void)ws_size;
    const int*   x       = (const int*)  d_in[0];
    const int*   edge    = (const int*)  d_in[1];
    const float* emb     = (const float*)d_in[3];
    const float* W1      = (const float*)d_in[4];
    const float* b1      = (const float*)d_in[5];
    const float* W2      = (const float*)d_in[6];
    const float* b2      = (const float*)d_in[7];
    const float* pool_w  = (const float*)d_in[8];
    const float* dense_W = (const float*)d_in[9];
    const float* dense_b = (const float*)d_in[10];
    const float* out_W   = (const float*)d_in[11];
    const float* out_b   = (const float*)d_in[12];
    float* outp = (float*)d_out;

    // workspace carve-up (~53 MB)
    float* embW      = (float*)d_ws;                 // FEAT*32
    float* Abuf      = embW + FEAT * G1D;            // N*32 (A' then h2... A')
    float* Bbuf      = Abuf + (size_t)NN * G1D;      // N*32 (chist, then B')
    float* dinv      = Bbuf + (size_t)NN * G2D;      // N
    int*   row_start = (int*)(dinv + NN);            // N
    int*   csr       = row_start + NN;               // E (+16 pad)
    float* scores    = (float*)(csr + NE + 16);      // N

    int* chist = (int*)Bbuf;                         // NB*8*NGRAPH = 1024000

    prep_kernel<<<512 + (FEAT * G1D) / 256, 256, 0, stream>>>(edge, chist, emb, W1, embW);
    scan_graph<<<NB, 256, 0, stream>>>(chist, dinv, row_start);
    mid_kernel<<<512 + (NN * 8) / 1024, 1024, 0, stream>>>(edge, row_start, csr,
                                                           x, embW, dinv, Abuf);
    agg1_kernel<<<NB * 32, 256, 0, stream>>>(Abuf, dinv, row_start, csr, b1, W2, Bbuf);
    agg2_kernel<<<NB * 32, 256, 0, stream>>>(Bbuf, dinv, row_start, csr, b2, pool_w, Abuf, scores);
    topk_pool_mlp<<<NB, 256, 0, stream>>>(Abuf, scores, dense_W, dense_b, out_W, out_b, outp);
}

// Round 3
// 249.750 us; speedup vs baseline: 1.0147x; 1.0147x over previous
//
#include <hip/hip_runtime.h>
#include <hip/hip_fp16.h>
#include <math.h>

#define NB 64
#define NGRAPH 2000
#define EGRAPH 64000
#define NN (NB*NGRAPH)      // 128000
#define NE (NB*EGRAPH)      // 4096000
#define KSEL 1600
#define FEAT 10000
#define EMBD 64
#define G1D 32
#define G2D 32
#define DENSED 64
#define NCLSD 10
#define NCHUNK 8
#define CHUNK_E (EGRAPH/NCHUNK)   // 8000
#define NQD 8                     // dst-ranges per graph (scatter)
#define QNODES (NGRAPH/NQD)       // 250
#define LOUT_CAP 10000            // staging cap (avg 8000, +24 sigma)

// R17: agg kernels are saturated on outstanding L2 misses (R15/R16: ILP and
// DS changes moved <=6%; VALU 29%, 32 waves/CU resident). Lever = line count:
// node-feature rows (A', B', h2) stored fp16 -> 64B/row = 1 cache line per
// edge gather (was 2). All accumulation f32; only materialized rows round.
// csr[] holds GLOBAL row byte offsets (src*64), padded by 16 ints.
// Graph->XCD ownership: graph g lives on XCD (g>>3).

__device__ __forceinline__ float4 ld_row8h(const char* base, unsigned byteoff)
{
    uint2 u = *(const uint2*)(base + byteoff);
    __half2 p0 = *(__half2*)&u.x;
    __half2 p1 = *(__half2*)&u.y;
    float2 f0 = __half22float2(p0);
    float2 f1 = __half22float2(p1);
    return make_float4(f0.x, f0.y, f1.x, f1.y);
}

__device__ __forceinline__ void st_row8h(__half* dst, float4 v)
{
    __half2 p0 = __floats2half2_rn(v.x, v.y);
    __half2 p1 = __floats2half2_rn(v.z, v.w);
    uint2 u;
    u.x = *(unsigned*)&p0;
    u.y = *(unsigned*)&p1;
    *(uint2*)dst = u;
}

// ---------------------------------------------------------------------------
// K1: prep = per-chunk LDS histogram of dst (blocks 0..511)
//          + embW = emb @ W1 (blocks 512..1761). 256 threads.
// ---------------------------------------------------------------------------
__global__ __launch_bounds__(256) void prep_kernel(const int* __restrict__ ei,
                                                   int* __restrict__ chist,
                                                   const float* __restrict__ emb,
                                                   const float* __restrict__ W1,
                                                   float* __restrict__ embW)
{
    __shared__ float shmem[2048];        // 8 KB union: hist[2000] / W1s[2048]
    const int tid = threadIdx.x;
    if (blockIdx.x < 512) {
        int* hist = (int*)shmem;
        const int lb = blockIdx.x;           // 512 blocks
        const int xcd = lb & 7, t = lb >> 3; // t in [0,64)
        const int g = xcd * 8 + (t >> 3);
        const int q = t & 7;
        const int base_e = g * EGRAPH + q * CHUNK_E;
        const int base_n = g * NGRAPH;
        for (int v = tid; v < NGRAPH; v += 256) hist[v] = 0;
        __syncthreads();
        for (int k = tid; k < CHUNK_E; k += 256) {
            int d = ei[NE + base_e + k];
            atomicAdd(&hist[d - base_n], 1);      // LDS atomic
        }
        __syncthreads();
        int* out = chist + (size_t)(g * NCHUNK + q) * NGRAPH;
        for (int v = tid; v < NGRAPH; v += 256) out[v] = hist[v];
    } else {
        float* W1s = shmem;
        for (int i = tid; i < EMBD * G1D; i += 256) W1s[i] = W1[i];
        __syncthreads();
        int id = (blockIdx.x - 512) * 256 + tid;
        int r = id >> 5, c = id & 31;
        if (r >= FEAT) return;
        const float* er = emb + r * EMBD;
        float acc = 0.f;
        #pragma unroll 8
        for (int k = 0; k < EMBD; ++k) acc += er[k] * W1s[k * G1D + c];
        embW[r * G1D + c] = acc;
    }
}

// ---------------------------------------------------------------------------
// K2: per-graph: deg = sum of 8 chunk hists -> dinv; exclusive scan ->
//      row_start. one block per graph.
// ---------------------------------------------------------------------------
__global__ __launch_bounds__(256) void scan_graph(const int* __restrict__ chist,
                                                  float* __restrict__ dinv,
                                                  int* __restrict__ row_start)
{
    __shared__ int hist[NGRAPH];
    __shared__ int csA[256];
    __shared__ int csB[256];
    const int b = (blockIdx.x & 7) * 8 + (blockIdx.x >> 3);   // XCD-local graph
    const int tid = threadIdx.x;
    const int base_n = b * NGRAPH, base_e = b * EGRAPH;
    const int* ch = chist + (size_t)b * NCHUNK * NGRAPH;

    for (int v = tid; v < NGRAPH; v += 256) {
        int tot = 0;
        #pragma unroll
        for (int q = 0; q < NCHUNK; ++q) tot += ch[q * NGRAPH + v];
        hist[v] = tot;
        dinv[base_n + v] = rsqrtf((float)(tot + 1));   // +1 self-loop
    }
    __syncthreads();
    if (tid < 250) {
        int s = 0;
        #pragma unroll
        for (int i = 0; i < 8; ++i) s += hist[tid * 8 + i];
        csA[tid] = s;
    }
    __syncthreads();
    int* sb = csA; int* db = csB;
    for (int off = 1; off < 256; off <<= 1) {
        int v = 0;
        if (tid < 250) { v = sb[tid]; if (tid >= off) v += sb[tid - off]; }
        if (tid < 250) db[tid] = v;
        __syncthreads();
        int* t = sb; sb = db; db = t;
    }
    if (tid < 250) {
        int run = (tid == 0) ? 0 : sb[tid - 1];
        #pragma unroll
        for (int i = 0; i < 8; ++i) {
            int idx = tid * 8 + i;
            int c = hist[idx];
            row_start[base_n + idx] = base_e + run;
            run += c;
        }
    }
}

// ---------------------------------------------------------------------------
// K3: mid = dst-range scatter with LDS staging (blocks 0..511)
//         + A' gather (blocks 512..1511). 1024 threads.
// scatter stores GLOBAL byte offset src*64 (fp16 rows).
// ---------------------------------------------------------------------------
__global__ __launch_bounds__(1024) void mid_kernel(const int* __restrict__ ei,
                                                   const int* __restrict__ row_start,
                                                   int* __restrict__ csr,
                                                   const int* __restrict__ x,
                                                   const float* __restrict__ embW,
                                                   const float* __restrict__ dinv,
                                                   __half* __restrict__ A)
{
    __shared__ int cur[QNODES];
    __shared__ int lout[LOUT_CAP];
    const int tid = threadIdx.x;
    if (blockIdx.x < 512) {
        const int lb = blockIdx.x;             // 512 blocks
        const int xcd = lb & 7, t = lb >> 3;   // t in [0,64)
        const int g = xcd * 8 + (t >> 3);
        const int qd = t & 7;
        const int base_n = g * NGRAPH;
        const int lo = qd * QNODES;
        const int base = row_start[base_n + lo];
        const int qend = (g == NB - 1 && qd == NQD - 1) ? NE
                         : row_start[base_n + lo + QNODES];
        for (int v = tid; v < QNODES; v += 1024)
            cur[v] = row_start[base_n + lo + v] - base;
        __syncthreads();
        const int4* srcp = (const int4*)(ei + g * EGRAPH);
        const int4* dstp = (const int4*)(ei + NE + g * EGRAPH);
        const int sub = base_n + lo;
        for (int k = tid; k < EGRAPH / 4; k += 1024) {
            int4 d4 = dstp[k];
            int4 s4 = srcp[k];
            int d, pos;
            d = d4.x - sub;
            if ((unsigned)d < (unsigned)QNODES) {
                pos = atomicAdd(&cur[d], 1);
                if (pos < LOUT_CAP) lout[pos] = s4.x << 6;
            }
            d = d4.y - sub;
            if ((unsigned)d < (unsigned)QNODES) {
                pos = atomicAdd(&cur[d], 1);
                if (pos < LOUT_CAP) lout[pos] = s4.y << 6;
            }
            d = d4.z - sub;
            if ((unsigned)d < (unsigned)QNODES) {
                pos = atomicAdd(&cur[d], 1);
                if (pos < LOUT_CAP) lout[pos] = s4.z << 6;
            }
            d = d4.w - sub;
            if ((unsigned)d < (unsigned)QNODES) {
                pos = atomicAdd(&cur[d], 1);
                if (pos < LOUT_CAP) lout[pos] = s4.w << 6;
            }
        }
        __syncthreads();
        int size = qend - base;
        if (size > LOUT_CAP) size = LOUT_CAP;   // safety clamp
        for (int i = tid; i < size; i += 1024)
            csr[base + i] = lout[i];
    } else {
        int id = (blockIdx.x - 512) * 1024 + tid;   // id = v*8 + r
        int v = id >> 3, r = id & 7;
        int xv = x[v];
        float dv = dinv[v];
        float4 e = ((const float4*)(embW + (size_t)xv * G1D))[r];
        e.x *= dv; e.y *= dv; e.z *= dv; e.w *= dv;
        st_row8h(A + (size_t)v * G1D + r * 4, e);
    }
}

// ---------------------------------------------------------------------------
// agg: half-wave (32 lanes) per node, 4 edge-slots x 8 lanes x 8B(4 fp16),
// 4-deep pipeline (16 edges/iter) + rolling next-node prefetch.
// csr entries are pre-shifted global byte offsets (src*64); csr padded 16.
// ---------------------------------------------------------------------------

// K4: layer-1 aggregation + ReLU + (h1 @ W2) * dinv -> B'
__global__ __launch_bounds__(256) void agg1_kernel(const __half* __restrict__ Ain,
                                                   const float* __restrict__ dinv,
                                                   const int* __restrict__ row_start,
                                                   const int* __restrict__ csr,
                                                   const float* __restrict__ b1,
                                                   const float* __restrict__ W2,
                                                   __half* __restrict__ Bout)
{
    __shared__ float hsh[8][G2D];           // per half-wave h row (1 KB, f32)
    const int lb = blockIdx.x;
    const int xcd = lb & 7, idx = lb >> 3;
    const int b = xcd * 8 + (idx >> 5);     // graph
    const int blk = idx & 31;
    const int half_id = threadIdx.x >> 5;   // 0..7
    const int hl = threadIdx.x & 31;        // lane in half-wave
    const int slot = hl >> 3;               // 0..3 edge slot
    const int r = hl & 7;                   // column quad: cols 4r..4r+3
    const int roff = r << 3;                // byte offset within fp16 row
    const char* Abase = (const char*)Ain;
    const int base_n = b * NGRAPH;
    const float4 bias4 = ((const float4*)b1)[r];

    // this lane's W2 column
    float w2c[G1D];
    #pragma unroll
    for (int k = 0; k < G1D; ++k) w2c[k] = W2[k * G2D + hl];

    const int vloc0 = blk * 64 + half_id * 8;
    int v = base_n + ((vloc0 < NGRAPH) ? vloc0 : NGRAPH - 1);
    int rs = row_start[v];
    int re = (v == NN - 1) ? NE : row_start[v + 1];
    int s0 = csr[rs + slot];
    int s1 = csr[rs + slot + 4];
    int s2 = csr[rs + slot + 8];
    int s3 = csr[rs + slot + 12];

    for (int i = 0; i < 8; ++i) {
        int vloc = vloc0 + i;
        if (vloc >= NGRAPH) break;
        int re_next = (v + 1 >= NN - 1) ? NE : row_start[v + 2];
        int n0 = csr[re + slot];
        int n1 = csr[re + slot + 4];
        int n2 = csr[re + slot + 8];
        int n3 = csr[re + slot + 12];

        int me = rs + ((re - rs) & ~15);    // 16-aligned unpredicated region
        float4 acc0 = make_float4(0.f, 0.f, 0.f, 0.f);
        float4 acc1 = make_float4(0.f, 0.f, 0.f, 0.f);
        float4 acc2 = make_float4(0.f, 0.f, 0.f, 0.f);
        float4 acc3 = make_float4(0.f, 0.f, 0.f, 0.f);
        if (slot == 0)
            acc0 = ld_row8h(Abase, (unsigned)(v * (G1D * 2) + roff)); // self-loop
        int j = rs + slot;
        while (j < me) {
            int jn = j + 16;
            int t0 = csr[jn];               // unguarded 16-ahead (csr padded)
            int t1 = csr[jn + 4];
            int t2 = csr[jn + 8];
            int t3 = csr[jn + 12];
            float4 a0 = ld_row8h(Abase, (unsigned)(s0 + roff));
            float4 a1 = ld_row8h(Abase, (unsigned)(s1 + roff));
            float4 a2 = ld_row8h(Abase, (unsigned)(s2 + roff));
            float4 a3 = ld_row8h(Abase, (unsigned)(s3 + roff));
            acc0.x += a0.x; acc0.y += a0.y; acc0.z += a0.z; acc0.w += a0.w;
            acc1.x += a1.x; acc1.y += a1.y; acc1.z += a1.z; acc1.w += a1.w;
            acc2.x += a2.x; acc2.y += a2.y; acc2.z += a2.z; acc2.w += a2.w;
            acc3.x += a3.x; acc3.y += a3.y; acc3.z += a3.z; acc3.w += a3.w;
            j = jn; s0 = t0; s1 = t1; s2 = t2; s3 = t3;
        }
        {   // tail: rem = re - me in [0,16); slot covers positions slot+4m
            int jt = me + slot;
            if (jt < re) {
                float4 a = ld_row8h(Abase, (unsigned)(s0 + roff));
                acc0.x += a.x; acc0.y += a.y; acc0.z += a.z; acc0.w += a.w;
            }
            if (jt + 4 < re) {
                float4 a = ld_row8h(Abase, (unsigned)(s1 + roff));
                acc1.x += a.x; acc1.y += a.y; acc1.z += a.z; acc1.w += a.w;
            }
            if (jt + 8 < re) {
                float4 a = ld_row8h(Abase, (unsigned)(s2 + roff));
                acc2.x += a.x; acc2.y += a.y; acc2.z += a.z; acc2.w += a.w;
            }
            if (jt + 12 < re) {
                float4 a = ld_row8h(Abase, (unsigned)(s3 + roff));
                acc3.x += a.x; acc3.y += a.y; acc3.z += a.z; acc3.w += a.w;
            }
        }
        float4 acc;
        acc.x = (acc0.x + acc1.x) + (acc2.x + acc3.x);
        acc.y = (acc0.y + acc1.y) + (acc2.y + acc3.y);
        acc.z = (acc0.z + acc1.z) + (acc2.z + acc3.z);
        acc.w = (acc0.w + acc1.w) + (acc2.w + acc3.w);
        #pragma unroll
        for (int off = 8; off <= 16; off <<= 1) {
            acc.x += __shfl_xor(acc.x, off, 32);
            acc.y += __shfl_xor(acc.y, off, 32);
            acc.z += __shfl_xor(acc.z, off, 32);
            acc.w += __shfl_xor(acc.w, off, 32);
        }
        float dv = dinv[v];
        if (slot == 0) {
            float4 h4;
            h4.x = fmaxf(dv * acc.x + bias4.x, 0.f);
            h4.y = fmaxf(dv * acc.y + bias4.y, 0.f);
            h4.z = fmaxf(dv * acc.z + bias4.z, 0.f);
            h4.w = fmaxf(dv * acc.w + bias4.w, 0.f);
            ((float4*)&hsh[half_id][0])[r] = h4;   // ds_write_b128
        }
        // same-wave in-order LDS: reads below see the write after lgkmcnt
        float o0 = 0.f, o1 = 0.f, o2 = 0.f, o3 = 0.f;
        const float4* hrow = (const float4*)&hsh[half_id][0];
        #pragma unroll
        for (int q = 0; q < 8; ++q) {              // 8 broadcast ds_read_b128
            float4 hh = hrow[q];
            o0 += hh.x * w2c[4 * q + 0];
            o1 += hh.y * w2c[4 * q + 1];
            o2 += hh.z * w2c[4 * q + 2];
            o3 += hh.w * w2c[4 * q + 3];
        }
        Bout[(size_t)v * G2D + hl] = __float2half(dv * ((o0 + o1) + (o2 + o3)));
        v = v + 1;
        rs = re; re = re_next; s0 = n0; s1 = n1; s2 = n2; s3 = n3;
    }
}

// K5: layer-2 aggregation + ReLU -> h2 (fp16) ; score = tanh(h2 . pw / ||pw||)
__global__ __launch_bounds__(256) void agg2_kernel(const __half* __restrict__ Bin,
                                                   const float* __restrict__ dinv,
                                                   const int* __restrict__ row_start,
                                                   const int* __restrict__ csr,
                                                   const float* __restrict__ b2,
                                                   const float* __restrict__ pool_w,
                                                   __half* __restrict__ h2out,
                                                   float* __restrict__ scores)
{
    const int lb = blockIdx.x;
    const int xcd = lb & 7, idx = lb >> 3;
    const int b = xcd * 8 + (idx >> 5);
    const int blk = idx & 31;
    const int half_id = threadIdx.x >> 5;
    const int hl = threadIdx.x & 31;
    const int slot = hl >> 3;
    const int r = hl & 7;
    const int roff = r << 3;
    const char* Bbase = (const char*)Bin;
    const int base_n = b * NGRAPH;
    const float4 bias4 = ((const float4*)b2)[r];
    const float4 pw4 = ((const float4*)pool_w)[r];

    float pw = pool_w[hl];
    float nsq = pw * pw;
    #pragma unroll
    for (int off = 16; off; off >>= 1) nsq += __shfl_xor(nsq, off, 32);
    const float inv_norm = rsqrtf(nsq);

    const int vloc0 = blk * 64 + half_id * 8;
    int v = base_n + ((vloc0 < NGRAPH) ? vloc0 : NGRAPH - 1);
    int rs = row_start[v];
    int re = (v == NN - 1) ? NE : row_start[v + 1];
    int s0 = csr[rs + slot];
    int s1 = csr[rs + slot + 4];
    int s2 = csr[rs + slot + 8];
    int s3 = csr[rs + slot + 12];

    for (int i = 0; i < 8; ++i) {
        int vloc = vloc0 + i;
        if (vloc >= NGRAPH) break;
        int re_next = (v + 1 >= NN - 1) ? NE : row_start[v + 2];
        int n0 = csr[re + slot];
        int n1 = csr[re + slot + 4];
        int n2 = csr[re + slot + 8];
        int n3 = csr[re + slot + 12];

        int me = rs + ((re - rs) & ~15);
        float4 acc0 = make_float4(0.f, 0.f, 0.f, 0.f);
        float4 acc1 = make_float4(0.f, 0.f, 0.f, 0.f);
        float4 acc2 = make_float4(0.f, 0.f, 0.f, 0.f);
        float4 acc3 = make_float4(0.f, 0.f, 0.f, 0.f);
        if (slot == 0)
            acc0 = ld_row8h(Bbase, (unsigned)(v * (G2D * 2) + roff));
        int j = rs + slot;
        while (j < me) {
            int jn = j + 16;
            int t0 = csr[jn];
            int t1 = csr[jn + 4];
            int t2 = csr[jn + 8];
            int t3 = csr[jn + 12];
            float4 a0 = ld_row8h(Bbase, (unsigned)(s0 + roff));
            float4 a1 = ld_row8h(Bbase, (unsigned)(s1 + roff));
            float4 a2 = ld_row8h(Bbase, (unsigned)(s2 + roff));
            float4 a3 = ld_row8h(Bbase, (unsigned)(s3 + roff));
            acc0.x += a0.x; acc0.y += a0.y; acc0.z += a0.z; acc0.w += a0.w;
            acc1.x += a1.x; acc1.y += a1.y; acc1.z += a1.z; acc1.w += a1.w;
            acc2.x += a2.x; acc2.y += a2.y; acc2.z += a2.z; acc2.w += a2.w;
            acc3.x += a3.x; acc3.y += a3.y; acc3.z += a3.z; acc3.w += a3.w;
            j = jn; s0 = t0; s1 = t1; s2 = t2; s3 = t3;
        }
        {
            int jt = me + slot;
            if (jt < re) {
                float4 a = ld_row8h(Bbase, (unsigned)(s0 + roff));
                acc0.x += a.x; acc0.y += a.y; acc0.z += a.z; acc0.w += a.w;
            }
            if (jt + 4 < re) {
                float4 a = ld_row8h(Bbase, (unsigned)(s1 + roff));
                acc1.x += a.x; acc1.y += a.y; acc1.z += a.z; acc1.w += a.w;
            }
            if (jt + 8 < re) {
                float4 a = ld_row8h(Bbase, (unsigned)(s2 + roff));
                acc2.x += a.x; acc2.y += a.y; acc2.z += a.z; acc2.w += a.w;
            }
            if (jt + 12 < re) {
                float4 a = ld_row8h(Bbase, (unsigned)(s3 + roff));
                acc3.x += a.x; acc3.y += a.y; acc3.z += a.z; acc3.w += a.w;
            }
        }
        float4 acc;
        acc.x = (acc0.x + acc1.x) + (acc2.x + acc3.x);
        acc.y = (acc0.y + acc1.y) + (acc2.y + acc3.y);
        acc.z = (acc0.z + acc1.z) + (acc2.z + acc3.z);
        acc.w = (acc0.w + acc1.w) + (acc2.w + acc3.w);
        #pragma unroll
        for (int off = 8; off <= 16; off <<= 1) {
            acc.x += __shfl_xor(acc.x, off, 32);
            acc.y += __shfl_xor(acc.y, off, 32);
            acc.z += __shfl_xor(acc.z, off, 32);
            acc.w += __shfl_xor(acc.w, off, 32);
        }
        float dv = dinv[v];
        float4 h4;
        h4.x = fmaxf(dv * acc.x + bias4.x, 0.f);
        h4.y = fmaxf(dv * acc.y + bias4.y, 0.f);
        h4.z = fmaxf(dv * acc.z + bias4.z, 0.f);
        h4.w = fmaxf(dv * acc.w + bias4.w, 0.f);
        if (slot == 0)
            st_row8h(h2out + (size_t)v * G2D + r * 4, h4);
        float t = h4.x * pw4.x + h4.y * pw4.y + h4.z * pw4.z + h4.w * pw4.w;
        t += __shfl_xor(t, 1, 32);
        t += __shfl_xor(t, 2, 32);
        t += __shfl_xor(t, 4, 32);
        if (hl == 0) scores[v] = tanhf(t * inv_norm);
        v = v + 1;
        rs = re; re = re_next; s0 = n0; s1 = n1; s2 = n2; s3 = n3;
    }
}

// ---------------------------------------------------------------------------
// K6: per-graph top-K(1600 of 2000) via 4-pass radix-256 select + parallel
// scaled max-pool + dense MLP. one block per graph, 256 threads.
// ---------------------------------------------------------------------------
__global__ __launch_bounds__(256) void topk_pool_mlp(const __half* __restrict__ h2,
                                                     const float* __restrict__ scores,
                                                     const float* __restrict__ dense_W,
                                                     const float* __restrict__ dense_b,
                                                     const float* __restrict__ out_W,
                                                     const float* __restrict__ out_b,
                                                     float* __restrict__ out)
{
    __shared__ unsigned keys[NGRAPH];
    __shared__ float    sval[NGRAPH];
    __shared__ unsigned char inc[NGRAPH];
    __shared__ int  hist[256];
    __shared__ int  csA[256];
    __shared__ int  csB[256];
    __shared__ int  sel[2];
    __shared__ int  redc[4];
    __shared__ float redf[32][32];
    __shared__ float gvec[32];
    __shared__ float dvec[DENSED];
    const int b = (blockIdx.x & 7) * 8 + (blockIdx.x >> 3);   // XCD-local graph
    const int tid = threadIdx.x;
    const int base_n = b * NGRAPH;

    for (int v = tid; v < NGRAPH; v += 256) {
        float f = scores[base_n + v];
        sval[v] = f;
        unsigned u = __float_as_uint(f);
        keys[v] = (u & 0x80000000u) ? ~u : (u | 0x80000000u);  // monotone map
    }
    __syncthreads();

    unsigned T = 0;
    int need = KSEL;
    #pragma unroll
    for (int pass = 0; pass < 4; ++pass) {
        const int s = 24 - pass * 8;
        const unsigned hi_mask = (pass == 0) ? 0u : (0xFFFFFFFFu << (s + 8));
        hist[tid] = 0;
        __syncthreads();
        for (int v = tid; v < NGRAPH; v += 256) {
            unsigned k = keys[v];
            if ((k & hi_mask) == (T & hi_mask))
                atomicAdd(&hist[(k >> s) & 255], 1);
        }
        __syncthreads();
        csA[tid] = hist[255 - tid];
        __syncthreads();
        int* sb = csA; int* db = csB;
        for (int off = 1; off < 256; off <<= 1) {
            int val = sb[tid];
            if (tid >= off) val += sb[tid - off];
            db[tid] = val;
            __syncthreads();
            int* t = sb; sb = db; db = t;
        }
        {
            const int d = tid;
            int suf_d = sb[255 - d];
            int suf_d1 = (d == 255) ? 0 : sb[254 - d];
            if (suf_d >= need && suf_d1 < need) {
                sel[0] = d;
                sel[1] = suf_d1;
            }
        }
        __syncthreads();
        T |= ((unsigned)sel[0]) << s;
        need -= sel[1];
        __syncthreads();
    }

    const int wid = tid >> 6, ln = tid & 63;
    int cg = 0, ce = 0;
    for (int v = tid; v < NGRAPH; v += 256) {
        cg += (keys[v] > T) ? 1 : 0;
        ce += (keys[v] == T) ? 1 : 0;
    }
    int packed = (cg << 16) | ce;
    #pragma unroll
    for (int off = 32; off; off >>= 1) packed += __shfl_down(packed, off, 64);
    if (ln == 0) redc[wid] = packed;
    __syncthreads();
    int tot = redc[0] + redc[1] + redc[2] + redc[3];
    int m_gt = tot >> 16, m_eq = tot & 0xffff;
    int needed = KSEL - m_gt;
    float fT = (T & 0x80000000u) ? __uint_as_float(T & 0x7fffffffu)
                                 : __uint_as_float(~T);
    if (m_eq == needed || fT == 0.0f) {
        for (int v = tid; v < NGRAPH; v += 256) inc[v] = (keys[v] >= T) ? 1 : 0;
    } else {
        if (tid == 0) {
            int take = 0;
            for (int v = 0; v < NGRAPH; ++v) {
                unsigned k = keys[v];
                if (k > T) inc[v] = 1;
                else if (k == T && take < needed) { inc[v] = 1; ++take; }
                else inc[v] = 0;
            }
        }
    }
    __syncthreads();

    {
        const int rowslot = tid >> 3;
        const int c4 = tid & 7;
        float4 m4 = make_float4(-INFINITY, -INFINITY, -INFINITY, -INFINITY);
        const char* h2base = (const char*)h2;
        for (int v = rowslot; v < NGRAPH; v += 32) {
            float4 hrow = ld_row8h(h2base,
                                   (unsigned)((base_n + v) * (G2D * 2) + c4 * 8));
            float sv = inc[v] ? sval[v] : 0.f;
            float big = inc[v] ? 0.f : -INFINITY;
            m4.x = fmaxf(m4.x, sv * hrow.x + big);
            m4.y = fmaxf(m4.y, sv * hrow.y + big);
            m4.z = fmaxf(m4.z, sv * hrow.z + big);
            m4.w = fmaxf(m4.w, sv * hrow.w + big);
        }
        redf[rowslot][c4 * 4 + 0] = m4.x;
        redf[rowslot][c4 * 4 + 1] = m4.y;
        redf[rowslot][c4 * 4 + 2] = m4.z;
        redf[rowslot][c4 * 4 + 3] = m4.w;
    }
    __syncthreads();
    if (tid < 32) {
        float g = redf[0][tid];
        #pragma unroll
        for (int rr = 1; rr < 32; ++rr) g = fmaxf(g, redf[rr][tid]);
        gvec[tid] = g;
    }
    __syncthreads();
    if (tid < DENSED) {
        float t = dense_b[tid];
        #pragma unroll
        for (int k = 0; k < G2D; ++k) t += gvec[k] * dense_W[k * DENSED + tid];
        dvec[tid] = fmaxf(t, 0.f);
    }
    __syncthreads();
    if (tid < NCLSD) {
        float o = out_b[tid];
        #pragma unroll
        for (int j = 0; j < DENSED; ++j) o += dvec[j] * out_W[j * NCLSD + tid];
        out[b * NCLSD + tid] = o;
    }
}

// ---------------------------------------------------------------------------
extern "C" void kernel_launch(void* const* d_in, const int* in_sizes, int n_in,
                              void* d_out, int out_size, void* d_ws, size_t ws_size,
                              hipStream_t stream)
{
    (void)in_sizes; (void)n_in; (void)out_size; (void)ws_size;
    const int*   x       = (const int*)  d_in[0];
    const int*   edge    = (const int*)  d_in[1];
    const float* emb     = (const float*)d_in[3];
    const float* W1      = (const float*)d_in[4];
    const float* b1      = (const float*)d_in[5];
    const float* W2      = (const float*)d_in[6];
    const float* b2      = (const float*)d_in[7];
    const float* pool_w  = (const float*)d_in[8];
    const float* dense_W = (const float*)d_in[9];
    const float* dense_b = (const float*)d_in[10];
    const float* out_W   = (const float*)d_in[11];
    const float* out_b   = (const float*)d_in[12];
    float* outp = (float*)d_out;

    // workspace carve-up (~36 MB), all offsets 64B-aligned
    char* ws = (char*)d_ws;
    float*  embW      = (float*)ws;                            // FEAT*32 f32 (1.28 MB)
    __half* Ah        = (__half*)(ws + 1280000);               // NN*32 fp16 (8.192 MB) — A', later h2
    __half* Bh        = (__half*)(ws + 1280000 + 8192000);     // NN*32 fp16 (8.192 MB) — B'
    float*  dinv      = (float*)(ws + 1280000 + 2*8192000);    // NN f32
    int*    row_start = (int*)((char*)dinv + (size_t)NN*4);    // NN
    int*    csr       = (int*)((char*)row_start + (size_t)NN*4); // NE (+16 pad)
    float*  scores    = (float*)((char*)csr + (size_t)(NE+16)*4); // NN

    int* chist = (int*)Bh;   // NB*8*NGRAPH ints (4.096 MB), consumed before agg1

    prep_kernel<<<512 + (FEAT * G1D) / 256, 256, 0, stream>>>(edge, chist, emb, W1, embW);
    scan_graph<<<NB, 256, 0, stream>>>(chist, dinv, row_start);
    mid_kernel<<<512 + (NN * 8) / 1024, 1024, 0, stream>>>(edge, row_start, csr,
                                                           x, embW, dinv, Ah);
    agg1_kernel<<<NB * 32, 256, 0, stream>>>(Ah, dinv, row_start, csr, b1, W2, Bh);
    agg2_kernel<<<NB * 32, 256, 0, stream>>>(Bh, dinv, row_start, csr, b2, pool_w, Ah, scores);
    topk_pool_mlp<<<NB, 256, 0, stream>>>(Ah, scores, dense_W, dense_b, out_W, out_b, outp);
}

// Round 4
// 226.022 us; speedup vs baseline: 1.1213x; 1.1050x over previous
//
#include <hip/hip_runtime.h>
#include <hip/hip_fp16.h>
#include <math.h>

#define NB 64
#define NGRAPH 2000
#define EGRAPH 64000
#define NN (NB*NGRAPH)      // 128000
#define NE (NB*EGRAPH)      // 4096000
#define KSEL 1600
#define FEAT 10000
#define EMBD 64
#define G1D 32
#define G2D 32
#define DENSED 64
#define NCLSD 10
#define NCHUNK 8
#define CHUNK_E (EGRAPH/NCHUNK)   // 8000
#define NQD 8                     // dst-ranges per graph (scatter)
#define QNODES (NGRAPH/NQD)       // 250
#define LOUT_CAP 10000            // staging cap (avg 8000, +24 sigma)
#define AGG_PARTS 4               // blocks per graph in agg kernels
#define NPP (NGRAPH/AGG_PARTS)    // 500 nodes per part

// R18: agg kernels spend their time in the scattered-gather machinery itself
// (R15/R16/R17: DS-ectomy, 4-deep ILP, fp16-halving all ~neutral; no pipe
// >41%). Fix: the whole graph feature table (2000 x 64B fp16 = 125 KiB) fits
// in LDS. agg1/agg2 now run 256 blocks (1/CU, 4/graph on the owning XCD),
// 1024 thr: stage table coalesced from L2 once, then ALL edge gathers are
// ds_read_b64 from LDS. csr[] holds GLOBAL row byte offsets (src*64),
// padded by 16 ints; agg subtracts the graph base to get LDS offsets.

__device__ __forceinline__ float4 ld_row8h(const char* base, unsigned byteoff)
{
    uint2 u = *(const uint2*)(base + byteoff);
    __half2 p0 = *(__half2*)&u.x;
    __half2 p1 = *(__half2*)&u.y;
    float2 f0 = __half22float2(p0);
    float2 f1 = __half22float2(p1);
    return make_float4(f0.x, f0.y, f1.x, f1.y);
}

__device__ __forceinline__ void st_row8h(__half* dst, float4 v)
{
    __half2 p0 = __floats2half2_rn(v.x, v.y);
    __half2 p1 = __floats2half2_rn(v.z, v.w);
    uint2 u;
    u.x = *(unsigned*)&p0;
    u.y = *(unsigned*)&p1;
    *(uint2*)dst = u;
}

// ---------------------------------------------------------------------------
// K1: prep = per-chunk LDS histogram of dst (blocks 0..511)
//          + embW = emb @ W1 (blocks 512..1761). 256 threads.
// ---------------------------------------------------------------------------
__global__ __launch_bounds__(256) void prep_kernel(const int* __restrict__ ei,
                                                   int* __restrict__ chist,
                                                   const float* __restrict__ emb,
                                                   const float* __restrict__ W1,
                                                   float* __restrict__ embW)
{
    __shared__ float shmem[2048];        // 8 KB union: hist[2000] / W1s[2048]
    const int tid = threadIdx.x;
    if (blockIdx.x < 512) {
        int* hist = (int*)shmem;
        const int lb = blockIdx.x;           // 512 blocks
        const int xcd = lb & 7, t = lb >> 3; // t in [0,64)
        const int g = xcd * 8 + (t >> 3);
        const int q = t & 7;
        const int base_e = g * EGRAPH + q * CHUNK_E;
        const int base_n = g * NGRAPH;
        for (int v = tid; v < NGRAPH; v += 256) hist[v] = 0;
        __syncthreads();
        for (int k = tid; k < CHUNK_E; k += 256) {
            int d = ei[NE + base_e + k];
            atomicAdd(&hist[d - base_n], 1);      // LDS atomic
        }
        __syncthreads();
        int* out = chist + (size_t)(g * NCHUNK + q) * NGRAPH;
        for (int v = tid; v < NGRAPH; v += 256) out[v] = hist[v];
    } else {
        float* W1s = shmem;
        for (int i = tid; i < EMBD * G1D; i += 256) W1s[i] = W1[i];
        __syncthreads();
        int id = (blockIdx.x - 512) * 256 + tid;
        int r = id >> 5, c = id & 31;
        if (r >= FEAT) return;
        const float* er = emb + r * EMBD;
        float acc = 0.f;
        #pragma unroll 8
        for (int k = 0; k < EMBD; ++k) acc += er[k] * W1s[k * G1D + c];
        embW[r * G1D + c] = acc;
    }
}

// ---------------------------------------------------------------------------
// K2: per-graph: deg = sum of 8 chunk hists -> dinv; exclusive scan ->
//      row_start. one block per graph.
// ---------------------------------------------------------------------------
__global__ __launch_bounds__(256) void scan_graph(const int* __restrict__ chist,
                                                  float* __restrict__ dinv,
                                                  int* __restrict__ row_start)
{
    __shared__ int hist[NGRAPH];
    __shared__ int csA[256];
    __shared__ int csB[256];
    const int b = (blockIdx.x & 7) * 8 + (blockIdx.x >> 3);   // XCD-local graph
    const int tid = threadIdx.x;
    const int base_n = b * NGRAPH, base_e = b * EGRAPH;
    const int* ch = chist + (size_t)b * NCHUNK * NGRAPH;

    for (int v = tid; v < NGRAPH; v += 256) {
        int tot = 0;
        #pragma unroll
        for (int q = 0; q < NCHUNK; ++q) tot += ch[q * NGRAPH + v];
        hist[v] = tot;
        dinv[base_n + v] = rsqrtf((float)(tot + 1));   // +1 self-loop
    }
    __syncthreads();
    if (tid < 250) {
        int s = 0;
        #pragma unroll
        for (int i = 0; i < 8; ++i) s += hist[tid * 8 + i];
        csA[tid] = s;
    }
    __syncthreads();
    int* sb = csA; int* db = csB;
    for (int off = 1; off < 256; off <<= 1) {
        int v = 0;
        if (tid < 250) { v = sb[tid]; if (tid >= off) v += sb[tid - off]; }
        if (tid < 250) db[tid] = v;
        __syncthreads();
        int* t = sb; sb = db; db = t;
    }
    if (tid < 250) {
        int run = (tid == 0) ? 0 : sb[tid - 1];
        #pragma unroll
        for (int i = 0; i < 8; ++i) {
            int idx = tid * 8 + i;
            int c = hist[idx];
            row_start[base_n + idx] = base_e + run;
            run += c;
        }
    }
}

// ---------------------------------------------------------------------------
// K3: mid = dst-range scatter with LDS staging (blocks 0..511)
//         + A' gather (blocks 512..1511). 1024 threads.
// scatter stores GLOBAL byte offset src*64 (fp16 rows).
// ---------------------------------------------------------------------------
__global__ __launch_bounds__(1024) void mid_kernel(const int* __restrict__ ei,
                                                   const int* __restrict__ row_start,
                                                   int* __restrict__ csr,
                                                   const int* __restrict__ x,
                                                   const float* __restrict__ embW,
                                                   const float* __restrict__ dinv,
                                                   __half* __restrict__ A)
{
    __shared__ int cur[QNODES];
    __shared__ int lout[LOUT_CAP];
    const int tid = threadIdx.x;
    if (blockIdx.x < 512) {
        const int lb = blockIdx.x;             // 512 blocks
        const int xcd = lb & 7, t = lb >> 3;   // t in [0,64)
        const int g = xcd * 8 + (t >> 3);
        const int qd = t & 7;
        const int base_n = g * NGRAPH;
        const int lo = qd * QNODES;
        const int base = row_start[base_n + lo];
        const int qend = (g == NB - 1 && qd == NQD - 1) ? NE
                         : row_start[base_n + lo + QNODES];
        for (int v = tid; v < QNODES; v += 1024)
            cur[v] = row_start[base_n + lo + v] - base;
        __syncthreads();
        const int4* srcp = (const int4*)(ei + g * EGRAPH);
        const int4* dstp = (const int4*)(ei + NE + g * EGRAPH);
        const int sub = base_n + lo;
        for (int k = tid; k < EGRAPH / 4; k += 1024) {
            int4 d4 = dstp[k];
            int4 s4 = srcp[k];
            int d, pos;
            d = d4.x - sub;
            if ((unsigned)d < (unsigned)QNODES) {
                pos = atomicAdd(&cur[d], 1);
                if (pos < LOUT_CAP) lout[pos] = s4.x << 6;
            }
            d = d4.y - sub;
            if ((unsigned)d < (unsigned)QNODES) {
                pos = atomicAdd(&cur[d], 1);
                if (pos < LOUT_CAP) lout[pos] = s4.y << 6;
            }
            d = d4.z - sub;
            if ((unsigned)d < (unsigned)QNODES) {
                pos = atomicAdd(&cur[d], 1);
                if (pos < LOUT_CAP) lout[pos] = s4.z << 6;
            }
            d = d4.w - sub;
            if ((unsigned)d < (unsigned)QNODES) {
                pos = atomicAdd(&cur[d], 1);
                if (pos < LOUT_CAP) lout[pos] = s4.w << 6;
            }
        }
        __syncthreads();
        int size = qend - base;
        if (size > LOUT_CAP) size = LOUT_CAP;   // safety clamp
        for (int i = tid; i < size; i += 1024)
            csr[base + i] = lout[i];
    } else {
        int id = (blockIdx.x - 512) * 1024 + tid;   // id = v*8 + r
        int v = id >> 3, r = id & 7;
        int xv = x[v];
        float dv = dinv[v];
        float4 e = ((const float4*)(embW + (size_t)xv * G1D))[r];
        e.x *= dv; e.y *= dv; e.z *= dv; e.w *= dv;
        st_row8h(A + (size_t)v * G1D + r * 4, e);
    }
}

// ---------------------------------------------------------------------------
// agg (R18): 256 blocks, 1024 threads, 1 block/CU. Block lb: xcd=lb&7,
// t=lb>>3 (0..31); graph b = xcd*8 + (t>>2), part = t&3 (500 nodes).
// Stage the graph's full fp16 table (2000 x 64B = 125 KiB) into LDS, then
// half-wave per node, 4 edge-slots x 8 lanes x 8B, 16 edges/iter, all
// gathers ds_read_b64. csr offsets are global byte offsets; subtract
// boff = base_n<<6 for LDS offsets.
// ---------------------------------------------------------------------------

// K4: layer-1 aggregation + ReLU + (h1 @ W2) * dinv -> B'
__global__ __launch_bounds__(1024) void agg1_kernel(const __half* __restrict__ Ain,
                                                    const float* __restrict__ dinv,
                                                    const int* __restrict__ row_start,
                                                    const int* __restrict__ csr,
                                                    const float* __restrict__ b1,
                                                    const float* __restrict__ W2,
                                                    __half* __restrict__ Bout)
{
    __shared__ uint4 table4[NGRAPH * 4];     // 128000 B: graph's A' rows fp16
    __shared__ float hsh[32][G2D];           // 4 KB: per half-wave h row
    const int lb = blockIdx.x;               // 256 blocks
    const int xcd = lb & 7, t = lb >> 3;     // t in [0,32)
    const int b = xcd * 8 + (t >> 2);        // graph
    const int part = t & 3;
    const int tid = threadIdx.x;
    const int base_n = b * NGRAPH;
    const int boff = base_n << 6;            // global byte offset of table

    {   // stage full graph table, coalesced (8000 x 16B)
        const uint4* src = (const uint4*)(Ain + (size_t)base_n * G1D);
        for (int i = tid; i < NGRAPH * 4; i += 1024) table4[i] = src[i];
    }
    __syncthreads();

    const char* Lbase = (const char*)table4;
    const int hw = tid >> 5;                 // 0..31 half-wave
    const int hl = tid & 31;
    const int slot = hl >> 3;                // 0..3 edge slot
    const int r = hl & 7;                    // column quad: cols 4r..4r+3
    const int roff = r << 3;                 // byte offset within fp16 row
    const float4 bias4 = ((const float4*)b1)[r];

    float w2c[G1D];
    #pragma unroll
    for (int k = 0; k < G1D; ++k) w2c[k] = W2[k * G2D + hl];

    const int vloc0 = part * NPP + hw * 16;  // 16 nodes per half-wave
    const int vend = part * NPP + NPP;
    int v = base_n + vloc0;
    int rs = row_start[v];
    int re = (v == NN - 1) ? NE : row_start[v + 1];
    int s0 = csr[rs + slot] - boff;
    int s1 = csr[rs + slot + 4] - boff;
    int s2 = csr[rs + slot + 8] - boff;
    int s3 = csr[rs + slot + 12] - boff;

    for (int i = 0; i < 16; ++i) {
        int vloc = vloc0 + i;
        if (vloc >= vend) break;
        int re_next = (v + 1 >= NN - 1) ? NE : row_start[v + 2];
        int n0 = csr[re + slot] - boff;
        int n1 = csr[re + slot + 4] - boff;
        int n2 = csr[re + slot + 8] - boff;
        int n3 = csr[re + slot + 12] - boff;

        int me = rs + ((re - rs) & ~15);     // 16-aligned unpredicated region
        float4 acc0 = make_float4(0.f, 0.f, 0.f, 0.f);
        float4 acc1 = make_float4(0.f, 0.f, 0.f, 0.f);
        float4 acc2 = make_float4(0.f, 0.f, 0.f, 0.f);
        float4 acc3 = make_float4(0.f, 0.f, 0.f, 0.f);
        if (slot == 0)
            acc0 = ld_row8h(Lbase, (unsigned)((vloc << 6) + roff)); // self-loop
        int j = rs + slot;
        while (j < me) {
            int jn = j + 16;
            int t0 = csr[jn] - boff;         // unguarded 16-ahead (csr padded)
            int t1 = csr[jn + 4] - boff;
            int t2 = csr[jn + 8] - boff;
            int t3 = csr[jn + 12] - boff;
            float4 a0 = ld_row8h(Lbase, (unsigned)(s0 + roff));
            float4 a1 = ld_row8h(Lbase, (unsigned)(s1 + roff));
            float4 a2 = ld_row8h(Lbase, (unsigned)(s2 + roff));
            float4 a3 = ld_row8h(Lbase, (unsigned)(s3 + roff));
            acc0.x += a0.x; acc0.y += a0.y; acc0.z += a0.z; acc0.w += a0.w;
            acc1.x += a1.x; acc1.y += a1.y; acc1.z += a1.z; acc1.w += a1.w;
            acc2.x += a2.x; acc2.y += a2.y; acc2.z += a2.z; acc2.w += a2.w;
            acc3.x += a3.x; acc3.y += a3.y; acc3.z += a3.z; acc3.w += a3.w;
            j = jn; s0 = t0; s1 = t1; s2 = t2; s3 = t3;
        }
        {   // tail: rem = re - me in [0,16)
            int jt = me + slot;
            if (jt < re) {
                float4 a = ld_row8h(Lbase, (unsigned)(s0 + roff));
                acc0.x += a.x; acc0.y += a.y; acc0.z += a.z; acc0.w += a.w;
            }
            if (jt + 4 < re) {
                float4 a = ld_row8h(Lbase, (unsigned)(s1 + roff));
                acc1.x += a.x; acc1.y += a.y; acc1.z += a.z; acc1.w += a.w;
            }
            if (jt + 8 < re) {
                float4 a = ld_row8h(Lbase, (unsigned)(s2 + roff));
                acc2.x += a.x; acc2.y += a.y; acc2.z += a.z; acc2.w += a.w;
            }
            if (jt + 12 < re) {
                float4 a = ld_row8h(Lbase, (unsigned)(s3 + roff));
                acc3.x += a.x; acc3.y += a.y; acc3.z += a.z; acc3.w += a.w;
            }
        }
        float4 acc;
        acc.x = (acc0.x + acc1.x) + (acc2.x + acc3.x);
        acc.y = (acc0.y + acc1.y) + (acc2.y + acc3.y);
        acc.z = (acc0.z + acc1.z) + (acc2.z + acc3.z);
        acc.w = (acc0.w + acc1.w) + (acc2.w + acc3.w);
        #pragma unroll
        for (int off = 8; off <= 16; off <<= 1) {
            acc.x += __shfl_xor(acc.x, off, 32);
            acc.y += __shfl_xor(acc.y, off, 32);
            acc.z += __shfl_xor(acc.z, off, 32);
            acc.w += __shfl_xor(acc.w, off, 32);
        }
        float dv = dinv[v];
        if (slot == 0) {
            float4 h4;
            h4.x = fmaxf(dv * acc.x + bias4.x, 0.f);
            h4.y = fmaxf(dv * acc.y + bias4.y, 0.f);
            h4.z = fmaxf(dv * acc.z + bias4.z, 0.f);
            h4.w = fmaxf(dv * acc.w + bias4.w, 0.f);
            ((float4*)&hsh[hw][0])[r] = h4;        // ds_write_b128
        }
        // same-wave in-order LDS: reads below see the write after lgkmcnt
        float o0 = 0.f, o1 = 0.f, o2 = 0.f, o3 = 0.f;
        const float4* hrow = (const float4*)&hsh[hw][0];
        #pragma unroll
        for (int q = 0; q < 8; ++q) {              // 8 broadcast ds_read_b128
            float4 hh = hrow[q];
            o0 += hh.x * w2c[4 * q + 0];
            o1 += hh.y * w2c[4 * q + 1];
            o2 += hh.z * w2c[4 * q + 2];
            o3 += hh.w * w2c[4 * q + 3];
        }
        Bout[(size_t)v * G2D + hl] = __float2half(dv * ((o0 + o1) + (o2 + o3)));
        v = v + 1;
        rs = re; re = re_next; s0 = n0; s1 = n1; s2 = n2; s3 = n3;
    }
}

// K5: layer-2 aggregation + ReLU -> h2 (fp16) ; score = tanh(h2 . pw / ||pw||)
__global__ __launch_bounds__(1024) void agg2_kernel(const __half* __restrict__ Bin,
                                                    const float* __restrict__ dinv,
                                                    const int* __restrict__ row_start,
                                                    const int* __restrict__ csr,
                                                    const float* __restrict__ b2,
                                                    const float* __restrict__ pool_w,
                                                    __half* __restrict__ h2out,
                                                    float* __restrict__ scores)
{
    __shared__ uint4 table4[NGRAPH * 4];     // 128000 B: graph's B' rows fp16
    const int lb = blockIdx.x;
    const int xcd = lb & 7, t = lb >> 3;
    const int b = xcd * 8 + (t >> 2);
    const int part = t & 3;
    const int tid = threadIdx.x;
    const int base_n = b * NGRAPH;
    const int boff = base_n << 6;

    {
        const uint4* src = (const uint4*)(Bin + (size_t)base_n * G1D);
        for (int i = tid; i < NGRAPH * 4; i += 1024) table4[i] = src[i];
    }
    __syncthreads();

    const char* Lbase = (const char*)table4;
    const int hw = tid >> 5;
    const int hl = tid & 31;
    const int slot = hl >> 3;
    const int r = hl & 7;
    const int roff = r << 3;
    const float4 bias4 = ((const float4*)b2)[r];
    const float4 pw4 = ((const float4*)pool_w)[r];

    float pw = pool_w[hl];
    float nsq = pw * pw;
    #pragma unroll
    for (int off = 16; off; off >>= 1) nsq += __shfl_xor(nsq, off, 32);
    const float inv_norm = rsqrtf(nsq);

    const int vloc0 = part * NPP + hw * 16;
    const int vend = part * NPP + NPP;
    int v = base_n + vloc0;
    int rs = row_start[v];
    int re = (v == NN - 1) ? NE : row_start[v + 1];
    int s0 = csr[rs + slot] - boff;
    int s1 = csr[rs + slot + 4] - boff;
    int s2 = csr[rs + slot + 8] - boff;
    int s3 = csr[rs + slot + 12] - boff;

    for (int i = 0; i < 16; ++i) {
        int vloc = vloc0 + i;
        if (vloc >= vend) break;
        int re_next = (v + 1 >= NN - 1) ? NE : row_start[v + 2];
        int n0 = csr[re + slot] - boff;
        int n1 = csr[re + slot + 4] - boff;
        int n2 = csr[re + slot + 8] - boff;
        int n3 = csr[re + slot + 12] - boff;

        int me = rs + ((re - rs) & ~15);
        float4 acc0 = make_float4(0.f, 0.f, 0.f, 0.f);
        float4 acc1 = make_float4(0.f, 0.f, 0.f, 0.f);
        float4 acc2 = make_float4(0.f, 0.f, 0.f, 0.f);
        float4 acc3 = make_float4(0.f, 0.f, 0.f, 0.f);
        if (slot == 0)
            acc0 = ld_row8h(Lbase, (unsigned)((vloc << 6) + roff));
        int j = rs + slot;
        while (j < me) {
            int jn = j + 16;
            int t0 = csr[jn] - boff;
            int t1 = csr[jn + 4] - boff;
            int t2 = csr[jn + 8] - boff;
            int t3 = csr[jn + 12] - boff;
            float4 a0 = ld_row8h(Lbase, (unsigned)(s0 + roff));
            float4 a1 = ld_row8h(Lbase, (unsigned)(s1 + roff));
            float4 a2 = ld_row8h(Lbase, (unsigned)(s2 + roff));
            float4 a3 = ld_row8h(Lbase, (unsigned)(s3 + roff));
            acc0.x += a0.x; acc0.y += a0.y; acc0.z += a0.z; acc0.w += a0.w;
            acc1.x += a1.x; acc1.y += a1.y; acc1.z += a1.z; acc1.w += a1.w;
            acc2.x += a2.x; acc2.y += a2.y; acc2.z += a2.z; acc2.w += a2.w;
            acc3.x += a3.x; acc3.y += a3.y; acc3.z += a3.z; acc3.w += a3.w;
            j = jn; s0 = t0; s1 = t1; s2 = t2; s3 = t3;
        }
        {
            int jt = me + slot;
            if (jt < re) {
                float4 a = ld_row8h(Lbase, (unsigned)(s0 + roff));
                acc0.x += a.x; acc0.y += a.y; acc0.z += a.z; acc0.w += a.w;
            }
            if (jt + 4 < re) {
                float4 a = ld_row8h(Lbase, (unsigned)(s1 + roff));
                acc1.x += a.x; acc1.y += a.y; acc1.z += a.z; acc1.w += a.w;
            }
            if (jt + 8 < re) {
                float4 a = ld_row8h(Lbase, (unsigned)(s2 + roff));
                acc2.x += a.x; acc2.y += a.y; acc2.z += a.z; acc2.w += a.w;
            }
            if (jt + 12 < re) {
                float4 a = ld_row8h(Lbase, (unsigned)(s3 + roff));
                acc3.x += a.x; acc3.y += a.y; acc3.z += a.z; acc3.w += a.w;
            }
        }
        float4 acc;
        acc.x = (acc0.x + acc1.x) + (acc2.x + acc3.x);
        acc.y = (acc0.y + acc1.y) + (acc2.y + acc3.y);
        acc.z = (acc0.z + acc1.z) + (acc2.z + acc3.z);
        acc.w = (acc0.w + acc1.w) + (acc2.w + acc3.w);
        #pragma unroll
        for (int off = 8; off <= 16; off <<= 1) {
            acc.x += __shfl_xor(acc.x, off, 32);
            acc.y += __shfl_xor(acc.y, off, 32);
            acc.z += __shfl_xor(acc.z, off, 32);
            acc.w += __shfl_xor(acc.w, off, 32);
        }
        float dv = dinv[v];
        float4 h4;
        h4.x = fmaxf(dv * acc.x + bias4.x, 0.f);
        h4.y = fmaxf(dv * acc.y + bias4.y, 0.f);
        h4.z = fmaxf(dv * acc.z + bias4.z, 0.f);
        h4.w = fmaxf(dv * acc.w + bias4.w, 0.f);
        if (slot == 0)
            st_row8h(h2out + (size_t)v * G2D + r * 4, h4);
        float tt = h4.x * pw4.x + h4.y * pw4.y + h4.z * pw4.z + h4.w * pw4.w;
        tt += __shfl_xor(tt, 1, 32);
        tt += __shfl_xor(tt, 2, 32);
        tt += __shfl_xor(tt, 4, 32);
        if (hl == 0) scores[v] = tanhf(tt * inv_norm);
        v = v + 1;
        rs = re; re = re_next; s0 = n0; s1 = n1; s2 = n2; s3 = n3;
    }
}

// ---------------------------------------------------------------------------
// K6: per-graph top-K(1600 of 2000) via 4-pass radix-256 select + parallel
// scaled max-pool + dense MLP. one block per graph, 256 threads.
// ---------------------------------------------------------------------------
__global__ __launch_bounds__(256) void topk_pool_mlp(const __half* __restrict__ h2,
                                                     const float* __restrict__ scores,
                                                     const float* __restrict__ dense_W,
                                                     const float* __restrict__ dense_b,
                                                     const float* __restrict__ out_W,
                                                     const float* __restrict__ out_b,
                                                     float* __restrict__ out)
{
    __shared__ unsigned keys[NGRAPH];
    __shared__ float    sval[NGRAPH];
    __shared__ unsigned char inc[NGRAPH];
    __shared__ int  hist[256];
    __shared__ int  csA[256];
    __shared__ int  csB[256];
    __shared__ int  sel[2];
    __shared__ int  redc[4];
    __shared__ float redf[32][32];
    __shared__ float gvec[32];
    __shared__ float dvec[DENSED];
    const int b = (blockIdx.x & 7) * 8 + (blockIdx.x >> 3);   // XCD-local graph
    const int tid = threadIdx.x;
    const int base_n = b * NGRAPH;

    for (int v = tid; v < NGRAPH; v += 256) {
        float f = scores[base_n + v];
        sval[v] = f;
        unsigned u = __float_as_uint(f);
        keys[v] = (u & 0x80000000u) ? ~u : (u | 0x80000000u);  // monotone map
    }
    __syncthreads();

    unsigned T = 0;
    int need = KSEL;
    #pragma unroll
    for (int pass = 0; pass < 4; ++pass) {
        const int s = 24 - pass * 8;
        const unsigned hi_mask = (pass == 0) ? 0u : (0xFFFFFFFFu << (s + 8));
        hist[tid] = 0;
        __syncthreads();
        for (int v = tid; v < NGRAPH; v += 256) {
            unsigned k = keys[v];
            if ((k & hi_mask) == (T & hi_mask))
                atomicAdd(&hist[(k >> s) & 255], 1);
        }
        __syncthreads();
        csA[tid] = hist[255 - tid];
        __syncthreads();
        int* sb = csA; int* db = csB;
        for (int off = 1; off < 256; off <<= 1) {
            int val = sb[tid];
            if (tid >= off) val += sb[tid - off];
            db[tid] = val;
            __syncthreads();
            int* t = sb; sb = db; db = t;
        }
        {
            const int d = tid;
            int suf_d = sb[255 - d];
            int suf_d1 = (d == 255) ? 0 : sb[254 - d];
            if (suf_d >= need && suf_d1 < need) {
                sel[0] = d;
                sel[1] = suf_d1;
            }
        }
        __syncthreads();
        T |= ((unsigned)sel[0]) << s;
        need -= sel[1];
        __syncthreads();
    }

    const int wid = tid >> 6, ln = tid & 63;
    int cg = 0, ce = 0;
    for (int v = tid; v < NGRAPH; v += 256) {
        cg += (keys[v] > T) ? 1 : 0;
        ce += (keys[v] == T) ? 1 : 0;
    }
    int packed = (cg << 16) | ce;
    #pragma unroll
    for (int off = 32; off; off >>= 1) packed += __shfl_down(packed, off, 64);
    if (ln == 0) redc[wid] = packed;
    __syncthreads();
    int tot = redc[0] + redc[1] + redc[2] + redc[3];
    int m_gt = tot >> 16, m_eq = tot & 0xffff;
    int needed = KSEL - m_gt;
    float fT = (T & 0x80000000u) ? __uint_as_float(T & 0x7fffffffu)
                                 : __uint_as_float(~T);
    if (m_eq == needed || fT == 0.0f) {
        for (int v = tid; v < NGRAPH; v += 256) inc[v] = (keys[v] >= T) ? 1 : 0;
    } else {
        if (tid == 0) {
            int take = 0;
            for (int v = 0; v < NGRAPH; ++v) {
                unsigned k = keys[v];
                if (k > T) inc[v] = 1;
                else if (k == T && take < needed) { inc[v] = 1; ++take; }
                else inc[v] = 0;
            }
        }
    }
    __syncthreads();

    {
        const int rowslot = tid >> 3;
        const int c4 = tid & 7;
        float4 m4 = make_float4(-INFINITY, -INFINITY, -INFINITY, -INFINITY);
        const char* h2base = (const char*)h2;
        for (int v = rowslot; v < NGRAPH; v += 32) {
            float4 hrow = ld_row8h(h2base,
                                   (unsigned)((base_n + v) * (G2D * 2) + c4 * 8));
            float sv = inc[v] ? sval[v] : 0.f;
            float big = inc[v] ? 0.f : -INFINITY;
            m4.x = fmaxf(m4.x, sv * hrow.x + big);
            m4.y = fmaxf(m4.y, sv * hrow.y + big);
            m4.z = fmaxf(m4.z, sv * hrow.z + big);
            m4.w = fmaxf(m4.w, sv * hrow.w + big);
        }
        redf[rowslot][c4 * 4 + 0] = m4.x;
        redf[rowslot][c4 * 4 + 1] = m4.y;
        redf[rowslot][c4 * 4 + 2] = m4.z;
        redf[rowslot][c4 * 4 + 3] = m4.w;
    }
    __syncthreads();
    if (tid < 32) {
        float g = redf[0][tid];
        #pragma unroll
        for (int rr = 1; rr < 32; ++rr) g = fmaxf(g, redf[rr][tid]);
        gvec[tid] = g;
    }
    __syncthreads();
    if (tid < DENSED) {
        float t = dense_b[tid];
        #pragma unroll
        for (int k = 0; k < G2D; ++k) t += gvec[k] * dense_W[k * DENSED + tid];
        dvec[tid] = fmaxf(t, 0.f);
    }
    __syncthreads();
    if (tid < NCLSD) {
        float o = out_b[tid];
        #pragma unroll
        for (int j = 0; j < DENSED; ++j) o += dvec[j] * out_W[j * NCLSD + tid];
        out[b * NCLSD + tid] = o;
    }
}

// ---------------------------------------------------------------------------
extern "C" void kernel_launch(void* const* d_in, const int* in_sizes, int n_in,
                              void* d_out, int out_size, void* d_ws, size_t ws_size,
                              hipStream_t stream)
{
    (void)in_sizes; (void)n_in; (void)out_size; (void)ws_size;
    const int*   x       = (const int*)  d_in[0];
    const int*   edge    = (const int*)  d_in[1];
    const float* emb     = (const float*)d_in[3];
    const float* W1      = (const float*)d_in[4];
    const float* b1      = (const float*)d_in[5];
    const float* W2      = (const float*)d_in[6];
    const float* b2      = (const float*)d_in[7];
    const float* pool_w  = (const float*)d_in[8];
    const float* dense_W = (const float*)d_in[9];
    const float* dense_b = (const float*)d_in[10];
    const float* out_W   = (const float*)d_in[11];
    const float* out_b   = (const float*)d_in[12];
    float* outp = (float*)d_out;

    // workspace carve-up (~36 MB), all offsets 64B-aligned
    char* ws = (char*)d_ws;
    float*  embW      = (float*)ws;                            // FEAT*32 f32 (1.28 MB)
    __half* Ah        = (__half*)(ws + 1280000);               // NN*32 fp16 (8.192 MB) — A', later h2
    __half* Bh        = (__half*)(ws + 1280000 + 8192000);     // NN*32 fp16 (8.192 MB) — B'
    float*  dinv      = (float*)(ws + 1280000 + 2*8192000);    // NN f32
    int*    row_start = (int*)((char*)dinv + (size_t)NN*4);    // NN
    int*    csr       = (int*)((char*)row_start + (size_t)NN*4); // NE (+16 pad)
    float*  scores    = (float*)((char*)csr + (size_t)(NE+16)*4); // NN

    int* chist = (int*)Bh;   // NB*8*NGRAPH ints (4.096 MB), consumed before agg1

    prep_kernel<<<512 + (FEAT * G1D) / 256, 256, 0, stream>>>(edge, chist, emb, W1, embW);
    scan_graph<<<NB, 256, 0, stream>>>(chist, dinv, row_start);
    mid_kernel<<<512 + (NN * 8) / 1024, 1024, 0, stream>>>(edge, row_start, csr,
                                                           x, embW, dinv, Ah);
    agg1_kernel<<<NB * AGG_PARTS, 1024, 0, stream>>>(Ah, dinv, row_start, csr, b1, W2, Bh);
    agg2_kernel<<<NB * AGG_PARTS, 1024, 0, stream>>>(Bh, dinv, row_start, csr, b2, pool_w, Ah, scores);
    topk_pool_mlp<<<NB, 256, 0, stream>>>(Ah, scores, dense_W, dense_b, out_W, out_b, outp);
}

// Round 5
// 224.697 us; speedup vs baseline: 1.1279x; 1.0059x over previous
//
#include <hip/hip_runtime.h>
#include <hip/hip_fp16.h>
#include <math.h>

#define NB 64
#define NGRAPH 2000
#define EGRAPH 64000
#define NN (NB*NGRAPH)      // 128000
#define NE (NB*EGRAPH)      // 4096000
#define KSEL 1600
#define FEAT 10000
#define EMBD 64
#define G1D 32
#define G2D 32
#define DENSED 64
#define NCLSD 10
#define NCHUNK 8
#define CHUNK_E (EGRAPH/NCHUNK)   // 8000
#define NQD 8                     // dst-ranges per graph (scatter)
#define QNODES (NGRAPH/NQD)       // 250
#define LOUT_CAP 10000            // staging cap (avg 8000, +24 sigma)
#define AGG_PARTS 4               // blocks per graph in agg kernels
#define NPP (NGRAPH/AGG_PARTS)    // 500 nodes per part
#define RSTRIDE 72                // skewed LDS row stride (bytes): kills the
                                  // 2-span 4-way bank conflict of 64B rows

// R19: R18's LDS-table agg left ~43us/kernel. Two residual costs attacked:
//  (1) 64B rows -> bank-span starts only at {0,16} -> structural 4-way
//      conflict on gathers. Rows now skewed to 72B (span start = 18*row%32,
//      16 distinct). csr[] stores GRAPH-LOCAL pre-skewed byte offsets
//      (src_local*72), so gather addr = entry + roff, no subtract.
//  (2) per-gather 4 cvt + 4 add f32 -> 2 v_pk_add_f16 (fp16 accumulate per
//      pipeline stage, ~8-add chains on 0.02-magnitude values; f32 combine
//      per node). Layer tables remain fp16 in global (linear 64B rows).

__device__ __forceinline__ float4 ld_row8h(const char* base, unsigned byteoff)
{
    uint2 u = *(const uint2*)(base + byteoff);
    __half2 p0 = *(__half2*)&u.x;
    __half2 p1 = *(__half2*)&u.y;
    float2 f0 = __half22float2(p0);
    float2 f1 = __half22float2(p1);
    return make_float4(f0.x, f0.y, f1.x, f1.y);
}

__device__ __forceinline__ void st_row8h(__half* dst, float4 v)
{
    __half2 p0 = __floats2half2_rn(v.x, v.y);
    __half2 p1 = __floats2half2_rn(v.z, v.w);
    uint2 u;
    u.x = *(unsigned*)&p0;
    u.y = *(unsigned*)&p1;
    *(uint2*)dst = u;
}

__device__ __forceinline__ void acc8h(const char* base, unsigned off,
                                      __half2& lo, __half2& hi)
{
    uint2 u = *(const uint2*)(base + off);
    lo = __hadd2(lo, *(__half2*)&u.x);
    hi = __hadd2(hi, *(__half2*)&u.y);
}

__device__ __forceinline__ float4 h2tof4(__half2 lo, __half2 hi)
{
    float2 a = __half22float2(lo);
    float2 b = __half22float2(hi);
    return make_float4(a.x, a.y, b.x, b.y);
}

// ---------------------------------------------------------------------------
// K1: prep = per-chunk LDS histogram of dst (blocks 0..511)
//          + embW = emb @ W1 (blocks 512..1761). 256 threads.
// ---------------------------------------------------------------------------
__global__ __launch_bounds__(256) void prep_kernel(const int* __restrict__ ei,
                                                   int* __restrict__ chist,
                                                   const float* __restrict__ emb,
                                                   const float* __restrict__ W1,
                                                   float* __restrict__ embW)
{
    __shared__ float shmem[2048];        // 8 KB union: hist[2000] / W1s[2048]
    const int tid = threadIdx.x;
    if (blockIdx.x < 512) {
        int* hist = (int*)shmem;
        const int lb = blockIdx.x;           // 512 blocks
        const int xcd = lb & 7, t = lb >> 3; // t in [0,64)
        const int g = xcd * 8 + (t >> 3);
        const int q = t & 7;
        const int base_e = g * EGRAPH + q * CHUNK_E;
        const int base_n = g * NGRAPH;
        for (int v = tid; v < NGRAPH; v += 256) hist[v] = 0;
        __syncthreads();
        for (int k = tid; k < CHUNK_E; k += 256) {
            int d = ei[NE + base_e + k];
            atomicAdd(&hist[d - base_n], 1);      // LDS atomic
        }
        __syncthreads();
        int* out = chist + (size_t)(g * NCHUNK + q) * NGRAPH;
        for (int v = tid; v < NGRAPH; v += 256) out[v] = hist[v];
    } else {
        float* W1s = shmem;
        for (int i = tid; i < EMBD * G1D; i += 256) W1s[i] = W1[i];
        __syncthreads();
        int id = (blockIdx.x - 512) * 256 + tid;
        int r = id >> 5, c = id & 31;
        if (r >= FEAT) return;
        const float* er = emb + r * EMBD;
        float acc = 0.f;
        #pragma unroll 8
        for (int k = 0; k < EMBD; ++k) acc += er[k] * W1s[k * G1D + c];
        embW[r * G1D + c] = acc;
    }
}

// ---------------------------------------------------------------------------
// K2: per-graph: deg = sum of 8 chunk hists -> dinv; exclusive scan ->
//      row_start. one block per graph.
// ---------------------------------------------------------------------------
__global__ __launch_bounds__(256) void scan_graph(const int* __restrict__ chist,
                                                  float* __restrict__ dinv,
                                                  int* __restrict__ row_start)
{
    __shared__ int hist[NGRAPH];
    __shared__ int csA[256];
    __shared__ int csB[256];
    const int b = (blockIdx.x & 7) * 8 + (blockIdx.x >> 3);   // XCD-local graph
    const int tid = threadIdx.x;
    const int base_n = b * NGRAPH, base_e = b * EGRAPH;
    const int* ch = chist + (size_t)b * NCHUNK * NGRAPH;

    for (int v = tid; v < NGRAPH; v += 256) {
        int tot = 0;
        #pragma unroll
        for (int q = 0; q < NCHUNK; ++q) tot += ch[q * NGRAPH + v];
        hist[v] = tot;
        dinv[base_n + v] = rsqrtf((float)(tot + 1));   // +1 self-loop
    }
    __syncthreads();
    if (tid < 250) {
        int s = 0;
        #pragma unroll
        for (int i = 0; i < 8; ++i) s += hist[tid * 8 + i];
        csA[tid] = s;
    }
    __syncthreads();
    int* sb = csA; int* db = csB;
    for (int off = 1; off < 256; off <<= 1) {
        int v = 0;
        if (tid < 250) { v = sb[tid]; if (tid >= off) v += sb[tid - off]; }
        if (tid < 250) db[tid] = v;
        __syncthreads();
        int* t = sb; sb = db; db = t;
    }
    if (tid < 250) {
        int run = (tid == 0) ? 0 : sb[tid - 1];
        #pragma unroll
        for (int i = 0; i < 8; ++i) {
            int idx = tid * 8 + i;
            int c = hist[idx];
            row_start[base_n + idx] = base_e + run;
            run += c;
        }
    }
}

// ---------------------------------------------------------------------------
// K3: mid = dst-range scatter with LDS staging (blocks 0..511)
//         + A' gather (blocks 512..1511). 1024 threads.
// scatter stores GRAPH-LOCAL skewed byte offset src_local*72.
// ---------------------------------------------------------------------------
__global__ __launch_bounds__(1024) void mid_kernel(const int* __restrict__ ei,
                                                   const int* __restrict__ row_start,
                                                   int* __restrict__ csr,
                                                   const int* __restrict__ x,
                                                   const float* __restrict__ embW,
                                                   const float* __restrict__ dinv,
                                                   __half* __restrict__ A)
{
    __shared__ int cur[QNODES];
    __shared__ int lout[LOUT_CAP];
    const int tid = threadIdx.x;
    if (blockIdx.x < 512) {
        const int lb = blockIdx.x;             // 512 blocks
        const int xcd = lb & 7, t = lb >> 3;   // t in [0,64)
        const int g = xcd * 8 + (t >> 3);
        const int qd = t & 7;
        const int base_n = g * NGRAPH;
        const int lo = qd * QNODES;
        const int base = row_start[base_n + lo];
        const int qend = (g == NB - 1 && qd == NQD - 1) ? NE
                         : row_start[base_n + lo + QNODES];
        for (int v = tid; v < QNODES; v += 1024)
            cur[v] = row_start[base_n + lo + v] - base;
        __syncthreads();
        const int4* srcp = (const int4*)(ei + g * EGRAPH);
        const int4* dstp = (const int4*)(ei + NE + g * EGRAPH);
        const int sub = base_n + lo;
        for (int k = tid; k < EGRAPH / 4; k += 1024) {
            int4 d4 = dstp[k];
            int4 s4 = srcp[k];
            int d, pos, sl;
            d = d4.x - sub;
            if ((unsigned)d < (unsigned)QNODES) {
                pos = atomicAdd(&cur[d], 1);
                sl = s4.x - base_n;
                if (pos < LOUT_CAP) lout[pos] = (sl << 6) + (sl << 3);
            }
            d = d4.y - sub;
            if ((unsigned)d < (unsigned)QNODES) {
                pos = atomicAdd(&cur[d], 1);
                sl = s4.y - base_n;
                if (pos < LOUT_CAP) lout[pos] = (sl << 6) + (sl << 3);
            }
            d = d4.z - sub;
            if ((unsigned)d < (unsigned)QNODES) {
                pos = atomicAdd(&cur[d], 1);
                sl = s4.z - base_n;
                if (pos < LOUT_CAP) lout[pos] = (sl << 6) + (sl << 3);
            }
            d = d4.w - sub;
            if ((unsigned)d < (unsigned)QNODES) {
                pos = atomicAdd(&cur[d], 1);
                sl = s4.w - base_n;
                if (pos < LOUT_CAP) lout[pos] = (sl << 6) + (sl << 3);
            }
        }
        __syncthreads();
        int size = qend - base;
        if (size > LOUT_CAP) size = LOUT_CAP;   // safety clamp
        for (int i = tid; i < size; i += 1024)
            csr[base + i] = lout[i];
    } else {
        int id = (blockIdx.x - 512) * 1024 + tid;   // id = v*8 + r
        int v = id >> 3, r = id & 7;
        int xv = x[v];
        float dv = dinv[v];
        float4 e = ((const float4*)(embW + (size_t)xv * G1D))[r];
        e.x *= dv; e.y *= dv; e.z *= dv; e.w *= dv;
        st_row8h(A + (size_t)v * G1D + r * 4, e);
    }
}

// ---------------------------------------------------------------------------
// agg (R19): 256 blocks, 1024 threads, 1/CU. graph b = xcd*8 + (t>>2),
// part = t&3. Stage graph table into SKEWED LDS (row stride 72B, 144 KB),
// then half-wave per node, 4 edge-slots x 8 lanes x 8B ds_read_b64,
// 16 edges/iter, fp16 packed accumulate, f32 combine + reduce.
// csr entries are local skewed byte offsets; addr = entry + roff.
// ---------------------------------------------------------------------------

// K4: layer-1 aggregation + ReLU + (h1 @ W2) * dinv -> B'
__global__ __launch_bounds__(1024) void agg1_kernel(const __half* __restrict__ Ain,
                                                    const float* __restrict__ dinv,
                                                    const int* __restrict__ row_start,
                                                    const int* __restrict__ csr,
                                                    const float* __restrict__ b1,
                                                    const float* __restrict__ W2,
                                                    __half* __restrict__ Bout)
{
    __shared__ uint2 table2[NGRAPH * 9];     // 144000 B skewed rows
    __shared__ float hsh[32][G2D];           // 4 KB: per half-wave h row
    const int lb = blockIdx.x;               // 256 blocks
    const int xcd = lb & 7, t = lb >> 3;     // t in [0,32)
    const int b = xcd * 8 + (t >> 2);        // graph
    const int part = t & 3;
    const int tid = threadIdx.x;
    const int base_n = b * NGRAPH;

    {   // stage full graph table (16000 x 8B), skewed write
        const uint2* src = (const uint2*)(Ain + (size_t)base_n * G1D);
        for (int i = tid; i < NGRAPH * 8; i += 1024)
            table2[(i >> 3) * 9 + (i & 7)] = src[i];
    }
    __syncthreads();

    const char* Lbase = (const char*)table2;
    const int hw = tid >> 5;                 // 0..31 half-wave
    const int hl = tid & 31;
    const int slot = hl >> 3;                // 0..3 edge slot
    const int r = hl & 7;                    // column quad: cols 4r..4r+3
    const int roff = r << 3;                 // byte offset within row
    const float4 bias4 = ((const float4*)b1)[r];

    float w2c[G1D];
    #pragma unroll
    for (int k = 0; k < G1D; ++k) w2c[k] = W2[k * G2D + hl];

    const __half2 z2 = __float2half2_rn(0.f);

    const int vloc0 = part * NPP + hw * 16;  // 16 nodes per half-wave
    const int vend = part * NPP + NPP;
    int v = base_n + vloc0;
    int rs = row_start[v];
    int re = (v == NN - 1) ? NE : row_start[v + 1];
    int s0 = csr[rs + slot];
    int s1 = csr[rs + slot + 4];
    int s2 = csr[rs + slot + 8];
    int s3 = csr[rs + slot + 12];

    for (int i = 0; i < 16; ++i) {
        int vloc = vloc0 + i;
        if (vloc >= vend) break;
        int re_next = (v + 1 >= NN - 1) ? NE : row_start[v + 2];
        int n0 = csr[re + slot];
        int n1 = csr[re + slot + 4];
        int n2 = csr[re + slot + 8];
        int n3 = csr[re + slot + 12];

        int me = rs + ((re - rs) & ~15);     // 16-aligned unpredicated region
        __half2 l0 = z2, h0 = z2, l1 = z2, h1 = z2;
        __half2 l2 = z2, h2 = z2, l3 = z2, h3 = z2;
        if (slot == 0)   // self-loop: own skewed row
            acc8h(Lbase, (unsigned)((vloc << 6) + (vloc << 3) + roff), l0, h0);
        int j = rs + slot;
        while (j < me) {
            int jn = j + 16;
            int t0 = csr[jn];                // unguarded 16-ahead (csr padded)
            int t1 = csr[jn + 4];
            int t2 = csr[jn + 8];
            int t3 = csr[jn + 12];
            acc8h(Lbase, (unsigned)(s0 + roff), l0, h0);
            acc8h(Lbase, (unsigned)(s1 + roff), l1, h1);
            acc8h(Lbase, (unsigned)(s2 + roff), l2, h2);
            acc8h(Lbase, (unsigned)(s3 + roff), l3, h3);
            j = jn; s0 = t0; s1 = t1; s2 = t2; s3 = t3;
        }
        {   // tail: rem = re - me in [0,16)
            int jt = me + slot;
            if (jt < re)      acc8h(Lbase, (unsigned)(s0 + roff), l0, h0);
            if (jt + 4 < re)  acc8h(Lbase, (unsigned)(s1 + roff), l1, h1);
            if (jt + 8 < re)  acc8h(Lbase, (unsigned)(s2 + roff), l2, h2);
            if (jt + 12 < re) acc8h(Lbase, (unsigned)(s3 + roff), l3, h3);
        }
        float4 f0 = h2tof4(l0, h0);
        float4 f1 = h2tof4(l1, h1);
        float4 f2 = h2tof4(l2, h2);
        float4 f3 = h2tof4(l3, h3);
        float4 acc;
        acc.x = (f0.x + f1.x) + (f2.x + f3.x);
        acc.y = (f0.y + f1.y) + (f2.y + f3.y);
        acc.z = (f0.z + f1.z) + (f2.z + f3.z);
        acc.w = (f0.w + f1.w) + (f2.w + f3.w);
        #pragma unroll
        for (int off = 8; off <= 16; off <<= 1) {
            acc.x += __shfl_xor(acc.x, off, 32);
            acc.y += __shfl_xor(acc.y, off, 32);
            acc.z += __shfl_xor(acc.z, off, 32);
            acc.w += __shfl_xor(acc.w, off, 32);
        }
        float dv = dinv[v];
        if (slot == 0) {
            float4 h4;
            h4.x = fmaxf(dv * acc.x + bias4.x, 0.f);
            h4.y = fmaxf(dv * acc.y + bias4.y, 0.f);
            h4.z = fmaxf(dv * acc.z + bias4.z, 0.f);
            h4.w = fmaxf(dv * acc.w + bias4.w, 0.f);
            ((float4*)&hsh[hw][0])[r] = h4;        // ds_write_b128
        }
        // same-wave in-order LDS: reads below see the write after lgkmcnt
        float o0 = 0.f, o1 = 0.f, o2 = 0.f, o3 = 0.f;
        const float4* hrow = (const float4*)&hsh[hw][0];
        #pragma unroll
        for (int q = 0; q < 8; ++q) {              // 8 broadcast ds_read_b128
            float4 hh = hrow[q];
            o0 += hh.x * w2c[4 * q + 0];
            o1 += hh.y * w2c[4 * q + 1];
            o2 += hh.z * w2c[4 * q + 2];
            o3 += hh.w * w2c[4 * q + 3];
        }
        Bout[(size_t)v * G2D + hl] = __float2half(dv * ((o0 + o1) + (o2 + o3)));
        v = v + 1;
        rs = re; re = re_next; s0 = n0; s1 = n1; s2 = n2; s3 = n3;
    }
}

// K5: layer-2 aggregation + ReLU -> h2 (fp16) ; score = tanh(h2 . pw / ||pw||)
__global__ __launch_bounds__(1024) void agg2_kernel(const __half* __restrict__ Bin,
                                                    const float* __restrict__ dinv,
                                                    const int* __restrict__ row_start,
                                                    const int* __restrict__ csr,
                                                    const float* __restrict__ b2,
                                                    const float* __restrict__ pool_w,
                                                    __half* __restrict__ h2out,
                                                    float* __restrict__ scores)
{
    __shared__ uint2 table2[NGRAPH * 9];     // 144000 B skewed rows
    const int lb = blockIdx.x;
    const int xcd = lb & 7, t = lb >> 3;
    const int b = xcd * 8 + (t >> 2);
    const int part = t & 3;
    const int tid = threadIdx.x;
    const int base_n = b * NGRAPH;

    {
        const uint2* src = (const uint2*)(Bin + (size_t)base_n * G1D);
        for (int i = tid; i < NGRAPH * 8; i += 1024)
            table2[(i >> 3) * 9 + (i & 7)] = src[i];
    }
    __syncthreads();

    const char* Lbase = (const char*)table2;
    const int hw = tid >> 5;
    const int hl = tid & 31;
    const int slot = hl >> 3;
    const int r = hl & 7;
    const int roff = r << 3;
    const float4 bias4 = ((const float4*)b2)[r];
    const float4 pw4 = ((const float4*)pool_w)[r];

    float pw = pool_w[hl];
    float nsq = pw * pw;
    #pragma unroll
    for (int off = 16; off; off >>= 1) nsq += __shfl_xor(nsq, off, 32);
    const float inv_norm = rsqrtf(nsq);

    const __half2 z2 = __float2half2_rn(0.f);

    const int vloc0 = part * NPP + hw * 16;
    const int vend = part * NPP + NPP;
    int v = base_n + vloc0;
    int rs = row_start[v];
    int re = (v == NN - 1) ? NE : row_start[v + 1];
    int s0 = csr[rs + slot];
    int s1 = csr[rs + slot + 4];
    int s2 = csr[rs + slot + 8];
    int s3 = csr[rs + slot + 12];

    for (int i = 0; i < 16; ++i) {
        int vloc = vloc0 + i;
        if (vloc >= vend) break;
        int re_next = (v + 1 >= NN - 1) ? NE : row_start[v + 2];
        int n0 = csr[re + slot];
        int n1 = csr[re + slot + 4];
        int n2 = csr[re + slot + 8];
        int n3 = csr[re + slot + 12];

        int me = rs + ((re - rs) & ~15);
        __half2 l0 = z2, h0 = z2, l1 = z2, h1 = z2;
        __half2 l2 = z2, h2 = z2, l3 = z2, h3 = z2;
        if (slot == 0)
            acc8h(Lbase, (unsigned)((vloc << 6) + (vloc << 3) + roff), l0, h0);
        int j = rs + slot;
        while (j < me) {
            int jn = j + 16;
            int t0 = csr[jn];
            int t1 = csr[jn + 4];
            int t2 = csr[jn + 8];
            int t3 = csr[jn + 12];
            acc8h(Lbase, (unsigned)(s0 + roff), l0, h0);
            acc8h(Lbase, (unsigned)(s1 + roff), l1, h1);
            acc8h(Lbase, (unsigned)(s2 + roff), l2, h2);
            acc8h(Lbase, (unsigned)(s3 + roff), l3, h3);
            j = jn; s0 = t0; s1 = t1; s2 = t2; s3 = t3;
        }
        {
            int jt = me + slot;
            if (jt < re)      acc8h(Lbase, (unsigned)(s0 + roff), l0, h0);
            if (jt + 4 < re)  acc8h(Lbase, (unsigned)(s1 + roff), l1, h1);
            if (jt + 8 < re)  acc8h(Lbase, (unsigned)(s2 + roff), l2, h2);
            if (jt + 12 < re) acc8h(Lbase, (unsigned)(s3 + roff), l3, h3);
        }
        float4 f0 = h2tof4(l0, h0);
        float4 f1 = h2tof4(l1, h1);
        float4 f2 = h2tof4(l2, h2);
        float4 f3 = h2tof4(l3, h3);
        float4 acc;
        acc.x = (f0.x + f1.x) + (f2.x + f3.x);
        acc.y = (f0.y + f1.y) + (f2.y + f3.y);
        acc.z = (f0.z + f1.z) + (f2.z + f3.z);
        acc.w = (f0.w + f1.w) + (f2.w + f3.w);
        #pragma unroll
        for (int off = 8; off <= 16; off <<= 1) {
            acc.x += __shfl_xor(acc.x, off, 32);
            acc.y += __shfl_xor(acc.y, off, 32);
            acc.z += __shfl_xor(acc.z, off, 32);
            acc.w += __shfl_xor(acc.w, off, 32);
        }
        float dv = dinv[v];
        float4 h4;
        h4.x = fmaxf(dv * acc.x + bias4.x, 0.f);
        h4.y = fmaxf(dv * acc.y + bias4.y, 0.f);
        h4.z = fmaxf(dv * acc.z + bias4.z, 0.f);
        h4.w = fmaxf(dv * acc.w + bias4.w, 0.f);
        if (slot == 0)
            st_row8h(h2out + (size_t)v * G2D + r * 4, h4);
        float tt = h4.x * pw4.x + h4.y * pw4.y + h4.z * pw4.z + h4.w * pw4.w;
        tt += __shfl_xor(tt, 1, 32);
        tt += __shfl_xor(tt, 2, 32);
        tt += __shfl_xor(tt, 4, 32);
        if (hl == 0) scores[v] = tanhf(tt * inv_norm);
        v = v + 1;
        rs = re; re = re_next; s0 = n0; s1 = n1; s2 = n2; s3 = n3;
    }
}

// ---------------------------------------------------------------------------
// K6: per-graph top-K(1600 of 2000) via 4-pass radix-256 select + parallel
// scaled max-pool + dense MLP. one block per graph, 256 threads.
// ---------------------------------------------------------------------------
__global__ __launch_bounds__(256) void topk_pool_mlp(const __half* __restrict__ h2,
                                                     const float* __restrict__ scores,
                                                     const float* __restrict__ dense_W,
                                                     const float* __restrict__ dense_b,
                                                     const float* __restrict__ out_W,
                                                     const float* __restrict__ out_b,
                                                     float* __restrict__ out)
{
    __shared__ unsigned keys[NGRAPH];
    __shared__ float    sval[NGRAPH];
    __shared__ unsigned char inc[NGRAPH];
    __shared__ int  hist[256];
    __shared__ int  csA[256];
    __shared__ int  csB[256];
    __shared__ int  sel[2];
    __shared__ int  redc[4];
    __shared__ float redf[32][32];
    __shared__ float gvec[32];
    __shared__ float dvec[DENSED];
    const int b = (blockIdx.x & 7) * 8 + (blockIdx.x >> 3);   // XCD-local graph
    const int tid = threadIdx.x;
    const int base_n = b * NGRAPH;

    for (int v = tid; v < NGRAPH; v += 256) {
        float f = scores[base_n + v];
        sval[v] = f;
        unsigned u = __float_as_uint(f);
        keys[v] = (u & 0x80000000u) ? ~u : (u | 0x80000000u);  // monotone map
    }
    __syncthreads();

    unsigned T = 0;
    int need = KSEL;
    #pragma unroll
    for (int pass = 0; pass < 4; ++pass) {
        const int s = 24 - pass * 8;
        const unsigned hi_mask = (pass == 0) ? 0u : (0xFFFFFFFFu << (s + 8));
        hist[tid] = 0;
        __syncthreads();
        for (int v = tid; v < NGRAPH; v += 256) {
            unsigned k = keys[v];
            if ((k & hi_mask) == (T & hi_mask))
                atomicAdd(&hist[(k >> s) & 255], 1);
        }
        __syncthreads();
        csA[tid] = hist[255 - tid];
        __syncthreads();
        int* sb = csA; int* db = csB;
        for (int off = 1; off < 256; off <<= 1) {
            int val = sb[tid];
            if (tid >= off) val += sb[tid - off];
            db[tid] = val;
            __syncthreads();
            int* t = sb; sb = db; db = t;
        }
        {
            const int d = tid;
            int suf_d = sb[255 - d];
            int suf_d1 = (d == 255) ? 0 : sb[254 - d];
            if (suf_d >= need && suf_d1 < need) {
                sel[0] = d;
                sel[1] = suf_d1;
            }
        }
        __syncthreads();
        T |= ((unsigned)sel[0]) << s;
        need -= sel[1];
        __syncthreads();
    }

    const int wid = tid >> 6, ln = tid & 63;
    int cg = 0, ce = 0;
    for (int v = tid; v < NGRAPH; v += 256) {
        cg += (keys[v] > T) ? 1 : 0;
        ce += (keys[v] == T) ? 1 : 0;
    }
    int packed = (cg << 16) | ce;
    #pragma unroll
    for (int off = 32; off; off >>= 1) packed += __shfl_down(packed, off, 64);
    if (ln == 0) redc[wid] = packed;
    __syncthreads();
    int tot = redc[0] + redc[1] + redc[2] + redc[3];
    int m_gt = tot >> 16, m_eq = tot & 0xffff;
    int needed = KSEL - m_gt;
    float fT = (T & 0x80000000u) ? __uint_as_float(T & 0x7fffffffu)
                                 : __uint_as_float(~T);
    if (m_eq == needed || fT == 0.0f) {
        for (int v = tid; v < NGRAPH; v += 256) inc[v] = (keys[v] >= T) ? 1 : 0;
    } else {
        if (tid == 0) {
            int take = 0;
            for (int v = 0; v < NGRAPH; ++v) {
                unsigned k = keys[v];
                if (k > T) inc[v] = 1;
                else if (k == T && take < needed) { inc[v] = 1; ++take; }
                else inc[v] = 0;
            }
        }
    }
    __syncthreads();

    {
        const int rowslot = tid >> 3;
        const int c4 = tid & 7;
        float4 m4 = make_float4(-INFINITY, -INFINITY, -INFINITY, -INFINITY);
        const char* h2base = (const char*)h2;
        for (int v = rowslot; v < NGRAPH; v += 32) {
            float4 hrow = ld_row8h(h2base,
                                   (unsigned)((base_n + v) * (G2D * 2) + c4 * 8));
            float sv = inc[v] ? sval[v] : 0.f;
            float big = inc[v] ? 0.f : -INFINITY;
            m4.x = fmaxf(m4.x, sv * hrow.x + big);
            m4.y = fmaxf(m4.y, sv * hrow.y + big);
            m4.z = fmaxf(m4.z, sv * hrow.z + big);
            m4.w = fmaxf(m4.w, sv * hrow.w + big);
        }
        redf[rowslot][c4 * 4 + 0] = m4.x;
        redf[rowslot][c4 * 4 + 1] = m4.y;
        redf[rowslot][c4 * 4 + 2] = m4.z;
        redf[rowslot][c4 * 4 + 3] = m4.w;
    }
    __syncthreads();
    if (tid < 32) {
        float g = redf[0][tid];
        #pragma unroll
        for (int rr = 1; rr < 32; ++rr) g = fmaxf(g, redf[rr][tid]);
        gvec[tid] = g;
    }
    __syncthreads();
    if (tid < DENSED) {
        float t = dense_b[tid];
        #pragma unroll
        for (int k = 0; k < G2D; ++k) t += gvec[k] * dense_W[k * DENSED + tid];
        dvec[tid] = fmaxf(t, 0.f);
    }
    __syncthreads();
    if (tid < NCLSD) {
        float o = out_b[tid];
        #pragma unroll
        for (int j = 0; j < DENSED; ++j) o += dvec[j] * out_W[j * NCLSD + tid];
        out[b * NCLSD + tid] = o;
    }
}

// ---------------------------------------------------------------------------
extern "C" void kernel_launch(void* const* d_in, const int* in_sizes, int n_in,
                              void* d_out, int out_size, void* d_ws, size_t ws_size,
                              hipStream_t stream)
{
    (void)in_sizes; (void)n_in; (void)out_size; (void)ws_size;
    const int*   x       = (const int*)  d_in[0];
    const int*   edge    = (const int*)  d_in[1];
    const float* emb     = (const float*)d_in[3];
    const float* W1      = (const float*)d_in[4];
    const float* b1      = (const float*)d_in[5];
    const float* W2      = (const float*)d_in[6];
    const float* b2      = (const float*)d_in[7];
    const float* pool_w  = (const float*)d_in[8];
    const float* dense_W = (const float*)d_in[9];
    const float* dense_b = (const float*)d_in[10];
    const float* out_W   = (const float*)d_in[11];
    const float* out_b   = (const float*)d_in[12];
    float* outp = (float*)d_out;

    // workspace carve-up (~36 MB), all offsets 64B-aligned
    char* ws = (char*)d_ws;
    float*  embW      = (float*)ws;                            // FEAT*32 f32 (1.28 MB)
    __half* Ah        = (__half*)(ws + 1280000);               // NN*32 fp16 (8.192 MB) — A', later h2
    __half* Bh        = (__half*)(ws + 1280000 + 8192000);     // NN*32 fp16 (8.192 MB) — B'
    float*  dinv      = (float*)(ws + 1280000 + 2*8192000);    // NN f32
    int*    row_start = (int*)((char*)dinv + (size_t)NN*4);    // NN
    int*    csr       = (int*)((char*)row_start + (size_t)NN*4); // NE (+16 pad)
    float*  scores    = (float*)((char*)csr + (size_t)(NE+16)*4); // NN

    int* chist = (int*)Bh;   // NB*8*NGRAPH ints (4.096 MB), consumed before agg1

    prep_kernel<<<512 + (FEAT * G1D) / 256, 256, 0, stream>>>(edge, chist, emb, W1, embW);
    scan_graph<<<NB, 256, 0, stream>>>(chist, dinv, row_start);
    mid_kernel<<<512 + (NN * 8) / 1024, 1024, 0, stream>>>(edge, row_start, csr,
                                                           x, embW, dinv, Ah);
    agg1_kernel<<<NB * AGG_PARTS, 1024, 0, stream>>>(Ah, dinv, row_start, csr, b1, W2, Bh);
    agg2_kernel<<<NB * AGG_PARTS, 1024, 0, stream>>>(Bh, dinv, row_start, csr, b2, pool_w, Ah, scores);
    topk_pool_mlp<<<NB, 256, 0, stream>>>(Ah, scores, dense_W, dense_b, out_W, out_b, outp);
}

// Round 6
// 213.843 us; speedup vs baseline: 1.1851x; 1.0508x over previous
//
#include <hip/hip_runtime.h>
#include <hip/hip_fp16.h>
#include <math.h>

#define NB 64
#define NGRAPH 2000
#define EGRAPH 64000
#define NN (NB*NGRAPH)      // 128000
#define NE (NB*EGRAPH)      // 4096000
#define KSEL 1600
#define FEAT 10000
#define EMBD 64
#define G1D 32
#define G2D 32
#define DENSED 64
#define NCLSD 10
#define NCHUNK 8
#define CHUNK_E (EGRAPH/NCHUNK)   // 8000
#define NQD 8                     // dst-ranges per graph (scatter)
#define QNODES (NGRAPH/NQD)       // 250
#define LOUT_CAP 10000            // staging cap (avg 8000, +24 sigma)
#define AGG_PARTS 4               // blocks per graph in agg kernels
#define NPP (NGRAPH/AGG_PARTS)    // 500 nodes per part

// R20: topk_pool_mlp was the tail risk (3 dispatches @166us, VALU 0.4%,
// occupancy 0.5% -> latency-stalled at 64x256). Now 64x1024: sweeps 8->2
// iters, pool 63->16 iters with 4x loads in flight, 2-stage max reduce.
// agg (R19): graph table in skewed LDS (72B rows), fp16 packed accumulate.
// csr[] holds GRAPH-LOCAL skewed byte offsets (src_local*72), padded 16.
// Graph->XCD ownership: graph g lives on XCD (g>>3).

__device__ __forceinline__ float4 ld_row8h(const char* base, unsigned byteoff)
{
    uint2 u = *(const uint2*)(base + byteoff);
    __half2 p0 = *(__half2*)&u.x;
    __half2 p1 = *(__half2*)&u.y;
    float2 f0 = __half22float2(p0);
    float2 f1 = __half22float2(p1);
    return make_float4(f0.x, f0.y, f1.x, f1.y);
}

__device__ __forceinline__ void st_row8h(__half* dst, float4 v)
{
    __half2 p0 = __floats2half2_rn(v.x, v.y);
    __half2 p1 = __floats2half2_rn(v.z, v.w);
    uint2 u;
    u.x = *(unsigned*)&p0;
    u.y = *(unsigned*)&p1;
    *(uint2*)dst = u;
}

__device__ __forceinline__ void acc8h(const char* base, unsigned off,
                                      __half2& lo, __half2& hi)
{
    uint2 u = *(const uint2*)(base + off);
    lo = __hadd2(lo, *(__half2*)&u.x);
    hi = __hadd2(hi, *(__half2*)&u.y);
}

__device__ __forceinline__ float4 h2tof4(__half2 lo, __half2 hi)
{
    float2 a = __half22float2(lo);
    float2 b = __half22float2(hi);
    return make_float4(a.x, a.y, b.x, b.y);
}

// ---------------------------------------------------------------------------
// K1: prep = per-chunk LDS histogram of dst (blocks 0..511)
//          + embW = emb @ W1 (blocks 512..1761). 256 threads.
// ---------------------------------------------------------------------------
__global__ __launch_bounds__(256) void prep_kernel(const int* __restrict__ ei,
                                                   int* __restrict__ chist,
                                                   const float* __restrict__ emb,
                                                   const float* __restrict__ W1,
                                                   float* __restrict__ embW)
{
    __shared__ float shmem[2048];        // 8 KB union: hist[2000] / W1s[2048]
    const int tid = threadIdx.x;
    if (blockIdx.x < 512) {
        int* hist = (int*)shmem;
        const int lb = blockIdx.x;           // 512 blocks
        const int xcd = lb & 7, t = lb >> 3; // t in [0,64)
        const int g = xcd * 8 + (t >> 3);
        const int q = t & 7;
        const int base_e = g * EGRAPH + q * CHUNK_E;
        const int base_n = g * NGRAPH;
        for (int v = tid; v < NGRAPH; v += 256) hist[v] = 0;
        __syncthreads();
        for (int k = tid; k < CHUNK_E; k += 256) {
            int d = ei[NE + base_e + k];
            atomicAdd(&hist[d - base_n], 1);      // LDS atomic
        }
        __syncthreads();
        int* out = chist + (size_t)(g * NCHUNK + q) * NGRAPH;
        for (int v = tid; v < NGRAPH; v += 256) out[v] = hist[v];
    } else {
        float* W1s = shmem;
        for (int i = tid; i < EMBD * G1D; i += 256) W1s[i] = W1[i];
        __syncthreads();
        int id = (blockIdx.x - 512) * 256 + tid;
        int r = id >> 5, c = id & 31;
        if (r >= FEAT) return;
        const float* er = emb + r * EMBD;
        float acc = 0.f;
        #pragma unroll 8
        for (int k = 0; k < EMBD; ++k) acc += er[k] * W1s[k * G1D + c];
        embW[r * G1D + c] = acc;
    }
}

// ---------------------------------------------------------------------------
// K2: per-graph: deg = sum of 8 chunk hists -> dinv; exclusive scan ->
//      row_start. one block per graph.
// ---------------------------------------------------------------------------
__global__ __launch_bounds__(256) void scan_graph(const int* __restrict__ chist,
                                                  float* __restrict__ dinv,
                                                  int* __restrict__ row_start)
{
    __shared__ int hist[NGRAPH];
    __shared__ int csA[256];
    __shared__ int csB[256];
    const int b = (blockIdx.x & 7) * 8 + (blockIdx.x >> 3);   // XCD-local graph
    const int tid = threadIdx.x;
    const int base_n = b * NGRAPH, base_e = b * EGRAPH;
    const int* ch = chist + (size_t)b * NCHUNK * NGRAPH;

    for (int v = tid; v < NGRAPH; v += 256) {
        int tot = 0;
        #pragma unroll
        for (int q = 0; q < NCHUNK; ++q) tot += ch[q * NGRAPH + v];
        hist[v] = tot;
        dinv[base_n + v] = rsqrtf((float)(tot + 1));   // +1 self-loop
    }
    __syncthreads();
    if (tid < 250) {
        int s = 0;
        #pragma unroll
        for (int i = 0; i < 8; ++i) s += hist[tid * 8 + i];
        csA[tid] = s;
    }
    __syncthreads();
    int* sb = csA; int* db = csB;
    for (int off = 1; off < 256; off <<= 1) {
        int v = 0;
        if (tid < 250) { v = sb[tid]; if (tid >= off) v += sb[tid - off]; }
        if (tid < 250) db[tid] = v;
        __syncthreads();
        int* t = sb; sb = db; db = t;
    }
    if (tid < 250) {
        int run = (tid == 0) ? 0 : sb[tid - 1];
        #pragma unroll
        for (int i = 0; i < 8; ++i) {
            int idx = tid * 8 + i;
            int c = hist[idx];
            row_start[base_n + idx] = base_e + run;
            run += c;
        }
    }
}

// ---------------------------------------------------------------------------
// K3: mid = dst-range scatter with LDS staging (blocks 0..511)
//         + A' gather (blocks 512..1511). 1024 threads.
// scatter stores GRAPH-LOCAL skewed byte offset src_local*72.
// ---------------------------------------------------------------------------
__global__ __launch_bounds__(1024) void mid_kernel(const int* __restrict__ ei,
                                                   const int* __restrict__ row_start,
                                                   int* __restrict__ csr,
                                                   const int* __restrict__ x,
                                                   const float* __restrict__ embW,
                                                   const float* __restrict__ dinv,
                                                   __half* __restrict__ A)
{
    __shared__ int cur[QNODES];
    __shared__ int lout[LOUT_CAP];
    const int tid = threadIdx.x;
    if (blockIdx.x < 512) {
        const int lb = blockIdx.x;             // 512 blocks
        const int xcd = lb & 7, t = lb >> 3;   // t in [0,64)
        const int g = xcd * 8 + (t >> 3);
        const int qd = t & 7;
        const int base_n = g * NGRAPH;
        const int lo = qd * QNODES;
        const int base = row_start[base_n + lo];
        const int qend = (g == NB - 1 && qd == NQD - 1) ? NE
                         : row_start[base_n + lo + QNODES];
        for (int v = tid; v < QNODES; v += 1024)
            cur[v] = row_start[base_n + lo + v] - base;
        __syncthreads();
        const int4* srcp = (const int4*)(ei + g * EGRAPH);
        const int4* dstp = (const int4*)(ei + NE + g * EGRAPH);
        const int sub = base_n + lo;
        for (int k = tid; k < EGRAPH / 4; k += 1024) {
            int4 d4 = dstp[k];
            int4 s4 = srcp[k];
            int d, pos, sl;
            d = d4.x - sub;
            if ((unsigned)d < (unsigned)QNODES) {
                pos = atomicAdd(&cur[d], 1);
                sl = s4.x - base_n;
                if (pos < LOUT_CAP) lout[pos] = (sl << 6) + (sl << 3);
            }
            d = d4.y - sub;
            if ((unsigned)d < (unsigned)QNODES) {
                pos = atomicAdd(&cur[d], 1);
                sl = s4.y - base_n;
                if (pos < LOUT_CAP) lout[pos] = (sl << 6) + (sl << 3);
            }
            d = d4.z - sub;
            if ((unsigned)d < (unsigned)QNODES) {
                pos = atomicAdd(&cur[d], 1);
                sl = s4.z - base_n;
                if (pos < LOUT_CAP) lout[pos] = (sl << 6) + (sl << 3);
            }
            d = d4.w - sub;
            if ((unsigned)d < (unsigned)QNODES) {
                pos = atomicAdd(&cur[d], 1);
                sl = s4.w - base_n;
                if (pos < LOUT_CAP) lout[pos] = (sl << 6) + (sl << 3);
            }
        }
        __syncthreads();
        int size = qend - base;
        if (size > LOUT_CAP) size = LOUT_CAP;   // safety clamp
        for (int i = tid; i < size; i += 1024)
            csr[base + i] = lout[i];
    } else {
        int id = (blockIdx.x - 512) * 1024 + tid;   // id = v*8 + r
        int v = id >> 3, r = id & 7;
        int xv = x[v];
        float dv = dinv[v];
        float4 e = ((const float4*)(embW + (size_t)xv * G1D))[r];
        e.x *= dv; e.y *= dv; e.z *= dv; e.w *= dv;
        st_row8h(A + (size_t)v * G1D + r * 4, e);
    }
}

// ---------------------------------------------------------------------------
// agg (R19): 256 blocks, 1024 threads, 1/CU. graph b = xcd*8 + (t>>2),
// part = t&3. Stage graph table into SKEWED LDS (row stride 72B, 144 KB),
// then half-wave per node, 4 edge-slots x 8 lanes x 8B ds_read_b64,
// 16 edges/iter, fp16 packed accumulate, f32 combine + reduce.
// csr entries are local skewed byte offsets; addr = entry + roff.
// ---------------------------------------------------------------------------

// K4: layer-1 aggregation + ReLU + (h1 @ W2) * dinv -> B'
__global__ __launch_bounds__(1024) void agg1_kernel(const __half* __restrict__ Ain,
                                                    const float* __restrict__ dinv,
                                                    const int* __restrict__ row_start,
                                                    const int* __restrict__ csr,
                                                    const float* __restrict__ b1,
                                                    const float* __restrict__ W2,
                                                    __half* __restrict__ Bout)
{
    __shared__ uint2 table2[NGRAPH * 9];     // 144000 B skewed rows
    __shared__ float hsh[32][G2D];           // 4 KB: per half-wave h row
    const int lb = blockIdx.x;               // 256 blocks
    const int xcd = lb & 7, t = lb >> 3;     // t in [0,32)
    const int b = xcd * 8 + (t >> 2);        // graph
    const int part = t & 3;
    const int tid = threadIdx.x;
    const int base_n = b * NGRAPH;

    {   // stage full graph table (16000 x 8B), skewed write
        const uint2* src = (const uint2*)(Ain + (size_t)base_n * G1D);
        for (int i = tid; i < NGRAPH * 8; i += 1024)
            table2[(i >> 3) * 9 + (i & 7)] = src[i];
    }
    __syncthreads();

    const char* Lbase = (const char*)table2;
    const int hw = tid >> 5;                 // 0..31 half-wave
    const int hl = tid & 31;
    const int slot = hl >> 3;                // 0..3 edge slot
    const int r = hl & 7;                    // column quad: cols 4r..4r+3
    const int roff = r << 3;                 // byte offset within row
    const float4 bias4 = ((const float4*)b1)[r];

    float w2c[G1D];
    #pragma unroll
    for (int k = 0; k < G1D; ++k) w2c[k] = W2[k * G2D + hl];

    const __half2 z2 = __float2half2_rn(0.f);

    const int vloc0 = part * NPP + hw * 16;  // 16 nodes per half-wave
    const int vend = part * NPP + NPP;
    int v = base_n + vloc0;
    int rs = row_start[v];
    int re = (v == NN - 1) ? NE : row_start[v + 1];
    int s0 = csr[rs + slot];
    int s1 = csr[rs + slot + 4];
    int s2 = csr[rs + slot + 8];
    int s3 = csr[rs + slot + 12];

    for (int i = 0; i < 16; ++i) {
        int vloc = vloc0 + i;
        if (vloc >= vend) break;
        int re_next = (v + 1 >= NN - 1) ? NE : row_start[v + 2];
        int n0 = csr[re + slot];
        int n1 = csr[re + slot + 4];
        int n2 = csr[re + slot + 8];
        int n3 = csr[re + slot + 12];

        int me = rs + ((re - rs) & ~15);     // 16-aligned unpredicated region
        __half2 l0 = z2, h0 = z2, l1 = z2, h1 = z2;
        __half2 l2 = z2, h2 = z2, l3 = z2, h3 = z2;
        if (slot == 0)   // self-loop: own skewed row
            acc8h(Lbase, (unsigned)((vloc << 6) + (vloc << 3) + roff), l0, h0);
        int j = rs + slot;
        while (j < me) {
            int jn = j + 16;
            int t0 = csr[jn];                // unguarded 16-ahead (csr padded)
            int t1 = csr[jn + 4];
            int t2 = csr[jn + 8];
            int t3 = csr[jn + 12];
            acc8h(Lbase, (unsigned)(s0 + roff), l0, h0);
            acc8h(Lbase, (unsigned)(s1 + roff), l1, h1);
            acc8h(Lbase, (unsigned)(s2 + roff), l2, h2);
            acc8h(Lbase, (unsigned)(s3 + roff), l3, h3);
            j = jn; s0 = t0; s1 = t1; s2 = t2; s3 = t3;
        }
        {   // tail: rem = re - me in [0,16)
            int jt = me + slot;
            if (jt < re)      acc8h(Lbase, (unsigned)(s0 + roff), l0, h0);
            if (jt + 4 < re)  acc8h(Lbase, (unsigned)(s1 + roff), l1, h1);
            if (jt + 8 < re)  acc8h(Lbase, (unsigned)(s2 + roff), l2, h2);
            if (jt + 12 < re) acc8h(Lbase, (unsigned)(s3 + roff), l3, h3);
        }
        float4 f0 = h2tof4(l0, h0);
        float4 f1 = h2tof4(l1, h1);
        float4 f2 = h2tof4(l2, h2);
        float4 f3 = h2tof4(l3, h3);
        float4 acc;
        acc.x = (f0.x + f1.x) + (f2.x + f3.x);
        acc.y = (f0.y + f1.y) + (f2.y + f3.y);
        acc.z = (f0.z + f1.z) + (f2.z + f3.z);
        acc.w = (f0.w + f1.w) + (f2.w + f3.w);
        #pragma unroll
        for (int off = 8; off <= 16; off <<= 1) {
            acc.x += __shfl_xor(acc.x, off, 32);
            acc.y += __shfl_xor(acc.y, off, 32);
            acc.z += __shfl_xor(acc.z, off, 32);
            acc.w += __shfl_xor(acc.w, off, 32);
        }
        float dv = dinv[v];
        if (slot == 0) {
            float4 h4;
            h4.x = fmaxf(dv * acc.x + bias4.x, 0.f);
            h4.y = fmaxf(dv * acc.y + bias4.y, 0.f);
            h4.z = fmaxf(dv * acc.z + bias4.z, 0.f);
            h4.w = fmaxf(dv * acc.w + bias4.w, 0.f);
            ((float4*)&hsh[hw][0])[r] = h4;        // ds_write_b128
        }
        // same-wave in-order LDS: reads below see the write after lgkmcnt
        float o0 = 0.f, o1 = 0.f, o2 = 0.f, o3 = 0.f;
        const float4* hrow = (const float4*)&hsh[hw][0];
        #pragma unroll
        for (int q = 0; q < 8; ++q) {              // 8 broadcast ds_read_b128
            float4 hh = hrow[q];
            o0 += hh.x * w2c[4 * q + 0];
            o1 += hh.y * w2c[4 * q + 1];
            o2 += hh.z * w2c[4 * q + 2];
            o3 += hh.w * w2c[4 * q + 3];
        }
        Bout[(size_t)v * G2D + hl] = __float2half(dv * ((o0 + o1) + (o2 + o3)));
        v = v + 1;
        rs = re; re = re_next; s0 = n0; s1 = n1; s2 = n2; s3 = n3;
    }
}

// K5: layer-2 aggregation + ReLU -> h2 (fp16) ; score = tanh(h2 . pw / ||pw||)
__global__ __launch_bounds__(1024) void agg2_kernel(const __half* __restrict__ Bin,
                                                    const float* __restrict__ dinv,
                                                    const int* __restrict__ row_start,
                                                    const int* __restrict__ csr,
                                                    const float* __restrict__ b2,
                                                    const float* __restrict__ pool_w,
                                                    __half* __restrict__ h2out,
                                                    float* __restrict__ scores)
{
    __shared__ uint2 table2[NGRAPH * 9];     // 144000 B skewed rows
    const int lb = blockIdx.x;
    const int xcd = lb & 7, t = lb >> 3;
    const int b = xcd * 8 + (t >> 2);
    const int part = t & 3;
    const int tid = threadIdx.x;
    const int base_n = b * NGRAPH;

    {
        const uint2* src = (const uint2*)(Bin + (size_t)base_n * G1D);
        for (int i = tid; i < NGRAPH * 8; i += 1024)
            table2[(i >> 3) * 9 + (i & 7)] = src[i];
    }
    __syncthreads();

    const char* Lbase = (const char*)table2;
    const int hw = tid >> 5;
    const int hl = tid & 31;
    const int slot = hl >> 3;
    const int r = hl & 7;
    const int roff = r << 3;
    const float4 bias4 = ((const float4*)b2)[r];
    const float4 pw4 = ((const float4*)pool_w)[r];

    float pw = pool_w[hl];
    float nsq = pw * pw;
    #pragma unroll
    for (int off = 16; off; off >>= 1) nsq += __shfl_xor(nsq, off, 32);
    const float inv_norm = rsqrtf(nsq);

    const __half2 z2 = __float2half2_rn(0.f);

    const int vloc0 = part * NPP + hw * 16;
    const int vend = part * NPP + NPP;
    int v = base_n + vloc0;
    int rs = row_start[v];
    int re = (v == NN - 1) ? NE : row_start[v + 1];
    int s0 = csr[rs + slot];
    int s1 = csr[rs + slot + 4];
    int s2 = csr[rs + slot + 8];
    int s3 = csr[rs + slot + 12];

    for (int i = 0; i < 16; ++i) {
        int vloc = vloc0 + i;
        if (vloc >= vend) break;
        int re_next = (v + 1 >= NN - 1) ? NE : row_start[v + 2];
        int n0 = csr[re + slot];
        int n1 = csr[re + slot + 4];
        int n2 = csr[re + slot + 8];
        int n3 = csr[re + slot + 12];

        int me = rs + ((re - rs) & ~15);
        __half2 l0 = z2, h0 = z2, l1 = z2, h1 = z2;
        __half2 l2 = z2, h2 = z2, l3 = z2, h3 = z2;
        if (slot == 0)
            acc8h(Lbase, (unsigned)((vloc << 6) + (vloc << 3) + roff), l0, h0);
        int j = rs + slot;
        while (j < me) {
            int jn = j + 16;
            int t0 = csr[jn];
            int t1 = csr[jn + 4];
            int t2 = csr[jn + 8];
            int t3 = csr[jn + 12];
            acc8h(Lbase, (unsigned)(s0 + roff), l0, h0);
            acc8h(Lbase, (unsigned)(s1 + roff), l1, h1);
            acc8h(Lbase, (unsigned)(s2 + roff), l2, h2);
            acc8h(Lbase, (unsigned)(s3 + roff), l3, h3);
            j = jn; s0 = t0; s1 = t1; s2 = t2; s3 = t3;
        }
        {
            int jt = me + slot;
            if (jt < re)      acc8h(Lbase, (unsigned)(s0 + roff), l0, h0);
            if (jt + 4 < re)  acc8h(Lbase, (unsigned)(s1 + roff), l1, h1);
            if (jt + 8 < re)  acc8h(Lbase, (unsigned)(s2 + roff), l2, h2);
            if (jt + 12 < re) acc8h(Lbase, (unsigned)(s3 + roff), l3, h3);
        }
        float4 f0 = h2tof4(l0, h0);
        float4 f1 = h2tof4(l1, h1);
        float4 f2 = h2tof4(l2, h2);
        float4 f3 = h2tof4(l3, h3);
        float4 acc;
        acc.x = (f0.x + f1.x) + (f2.x + f3.x);
        acc.y = (f0.y + f1.y) + (f2.y + f3.y);
        acc.z = (f0.z + f1.z) + (f2.z + f3.z);
        acc.w = (f0.w + f1.w) + (f2.w + f3.w);
        #pragma unroll
        for (int off = 8; off <= 16; off <<= 1) {
            acc.x += __shfl_xor(acc.x, off, 32);
            acc.y += __shfl_xor(acc.y, off, 32);
            acc.z += __shfl_xor(acc.z, off, 32);
            acc.w += __shfl_xor(acc.w, off, 32);
        }
        float dv = dinv[v];
        float4 h4;
        h4.x = fmaxf(dv * acc.x + bias4.x, 0.f);
        h4.y = fmaxf(dv * acc.y + bias4.y, 0.f);
        h4.z = fmaxf(dv * acc.z + bias4.z, 0.f);
        h4.w = fmaxf(dv * acc.w + bias4.w, 0.f);
        if (slot == 0)
            st_row8h(h2out + (size_t)v * G2D + r * 4, h4);
        float tt = h4.x * pw4.x + h4.y * pw4.y + h4.z * pw4.z + h4.w * pw4.w;
        tt += __shfl_xor(tt, 1, 32);
        tt += __shfl_xor(tt, 2, 32);
        tt += __shfl_xor(tt, 4, 32);
        if (hl == 0) scores[v] = tanhf(tt * inv_norm);
        v = v + 1;
        rs = re; re = re_next; s0 = n0; s1 = n1; s2 = n2; s3 = n3;
    }
}

// ---------------------------------------------------------------------------
// K6 (R20): per-graph top-K via 4-pass radix-256 select + scaled max-pool +
// dense MLP. one block per graph, 1024 threads (was 256): sweeps 2 iters,
// pool 16 iters with 4x MLP, 2-stage max reduce.
// ---------------------------------------------------------------------------
__global__ __launch_bounds__(1024) void topk_pool_mlp(const __half* __restrict__ h2,
                                                      const float* __restrict__ scores,
                                                      const float* __restrict__ dense_W,
                                                      const float* __restrict__ dense_b,
                                                      const float* __restrict__ out_W,
                                                      const float* __restrict__ out_b,
                                                      float* __restrict__ out)
{
    __shared__ unsigned keys[NGRAPH];
    __shared__ float    sval[NGRAPH];
    __shared__ unsigned char inc[NGRAPH];
    __shared__ int  hist[256];
    __shared__ int  csA[256];
    __shared__ int  csB[256];
    __shared__ int  sel[2];
    __shared__ int  redc[16];
    __shared__ float redf[128][32];          // 16 KB
    __shared__ float redp[8][32];
    __shared__ float gvec[32];
    __shared__ float dvec[DENSED];
    const int b = (blockIdx.x & 7) * 8 + (blockIdx.x >> 3);   // XCD-local graph
    const int tid = threadIdx.x;
    const int base_n = b * NGRAPH;

    for (int v = tid; v < NGRAPH; v += 1024) {      // 2 iters
        float f = scores[base_n + v];
        sval[v] = f;
        unsigned u = __float_as_uint(f);
        keys[v] = (u & 0x80000000u) ? ~u : (u | 0x80000000u);  // monotone map
    }
    __syncthreads();

    unsigned T = 0;
    int need = KSEL;
    #pragma unroll
    for (int pass = 0; pass < 4; ++pass) {
        const int s = 24 - pass * 8;
        const unsigned hi_mask = (pass == 0) ? 0u : (0xFFFFFFFFu << (s + 8));
        if (tid < 256) hist[tid] = 0;
        __syncthreads();
        for (int v = tid; v < NGRAPH; v += 1024) {  // 2 iters
            unsigned k = keys[v];
            if ((k & hi_mask) == (T & hi_mask))
                atomicAdd(&hist[(k >> s) & 255], 1);
        }
        __syncthreads();
        if (tid < 256) csA[tid] = hist[255 - tid];
        __syncthreads();
        int* sb = csA; int* db = csB;
        for (int off = 1; off < 256; off <<= 1) {
            int val = 0;
            if (tid < 256) {
                val = sb[tid];
                if (tid >= off) val += sb[tid - off];
                db[tid] = val;
            }
            __syncthreads();
            int* t = sb; sb = db; db = t;
        }
        if (tid < 256) {
            const int d = tid;
            int suf_d = sb[255 - d];
            int suf_d1 = (d == 255) ? 0 : sb[254 - d];
            if (suf_d >= need && suf_d1 < need) {
                sel[0] = d;
                sel[1] = suf_d1;
            }
        }
        __syncthreads();
        T |= ((unsigned)sel[0]) << s;
        need -= sel[1];
        __syncthreads();
    }

    const int wid = tid >> 6, ln = tid & 63;        // 16 waves
    int cg = 0, ce = 0;
    for (int v = tid; v < NGRAPH; v += 1024) {
        cg += (keys[v] > T) ? 1 : 0;
        ce += (keys[v] == T) ? 1 : 0;
    }
    int packed = (cg << 16) | ce;
    #pragma unroll
    for (int off = 32; off; off >>= 1) packed += __shfl_down(packed, off, 64);
    if (ln == 0) redc[wid] = packed;
    __syncthreads();
    int tot = 0;
    #pragma unroll
    for (int w = 0; w < 16; ++w) tot += redc[w];
    int m_gt = tot >> 16, m_eq = tot & 0xffff;
    int needed = KSEL - m_gt;
    float fT = (T & 0x80000000u) ? __uint_as_float(T & 0x7fffffffu)
                                 : __uint_as_float(~T);
    if (m_eq == needed || fT == 0.0f) {
        for (int v = tid; v < NGRAPH; v += 1024) inc[v] = (keys[v] >= T) ? 1 : 0;
    } else {
        if (tid == 0) {
            int take = 0;
            for (int v = 0; v < NGRAPH; ++v) {
                unsigned k = keys[v];
                if (k > T) inc[v] = 1;
                else if (k == T && take < needed) { inc[v] = 1; ++take; }
                else inc[v] = 0;
            }
        }
    }
    __syncthreads();

    {
        const int rowslot = tid >> 3;       // 0..127
        const int c4 = tid & 7;
        float4 m4 = make_float4(-INFINITY, -INFINITY, -INFINITY, -INFINITY);
        const char* h2base = (const char*)h2;
        for (int v = rowslot; v < NGRAPH; v += 128) {   // 16 iters
            float4 hrow = ld_row8h(h2base,
                                   (unsigned)((base_n + v) * (G2D * 2) + c4 * 8));
            float sv = inc[v] ? sval[v] : 0.f;
            float big = inc[v] ? 0.f : -INFINITY;
            m4.x = fmaxf(m4.x, sv * hrow.x + big);
            m4.y = fmaxf(m4.y, sv * hrow.y + big);
            m4.z = fmaxf(m4.z, sv * hrow.z + big);
            m4.w = fmaxf(m4.w, sv * hrow.w + big);
        }
        redf[rowslot][c4 * 4 + 0] = m4.x;
        redf[rowslot][c4 * 4 + 1] = m4.y;
        redf[rowslot][c4 * 4 + 2] = m4.z;
        redf[rowslot][c4 * 4 + 3] = m4.w;
    }
    __syncthreads();
    if (tid < 256) {
        const int col = tid & 31, part = tid >> 5;  // 8 parts x 16 rows
        float g = redf[part * 16][col];
        #pragma unroll
        for (int rr = 1; rr < 16; ++rr) g = fmaxf(g, redf[part * 16 + rr][col]);
        redp[part][col] = g;
    }
    __syncthreads();
    if (tid < 32) {
        float g = redp[0][tid];
        #pragma unroll
        for (int p = 1; p < 8; ++p) g = fmaxf(g, redp[p][tid]);
        gvec[tid] = g;
    }
    __syncthreads();
    if (tid < DENSED) {
        float t = dense_b[tid];
        #pragma unroll
        for (int k = 0; k < G2D; ++k) t += gvec[k] * dense_W[k * DENSED + tid];
        dvec[tid] = fmaxf(t, 0.f);
    }
    __syncthreads();
    if (tid < NCLSD) {
        float o = out_b[tid];
        #pragma unroll
        for (int j = 0; j < DENSED; ++j) o += dvec[j] * out_W[j * NCLSD + tid];
        out[b * NCLSD + tid] = o;
    }
}

// ---------------------------------------------------------------------------
extern "C" void kernel_launch(void* const* d_in, const int* in_sizes, int n_in,
                              void* d_out, int out_size, void* d_ws, size_t ws_size,
                              hipStream_t stream)
{
    (void)in_sizes; (void)n_in; (void)out_size; (void)ws_size;
    const int*   x       = (const int*)  d_in[0];
    const int*   edge    = (const int*)  d_in[1];
    const float* emb     = (const float*)d_in[3];
    const float* W1      = (const float*)d_in[4];
    const float* b1      = (const float*)d_in[5];
    const float* W2      = (const float*)d_in[6];
    const float* b2      = (const float*)d_in[7];
    const float* pool_w  = (const float*)d_in[8];
    const float* dense_W = (const float*)d_in[9];
    const float* dense_b = (const float*)d_in[10];
    const float* out_W   = (const float*)d_in[11];
    const float* out_b   = (const float*)d_in[12];
    float* outp = (float*)d_out;

    // workspace carve-up (~36 MB), all offsets 64B-aligned
    char* ws = (char*)d_ws;
    float*  embW      = (float*)ws;                            // FEAT*32 f32 (1.28 MB)
    __half* Ah        = (__half*)(ws + 1280000);               // NN*32 fp16 (8.192 MB) — A', later h2
    __half* Bh        = (__half*)(ws + 1280000 + 8192000);     // NN*32 fp16 (8.192 MB) — B'
    float*  dinv      = (float*)(ws + 1280000 + 2*8192000);    // NN f32
    int*    row_start = (int*)((char*)dinv + (size_t)NN*4);    // NN
    int*    csr       = (int*)((char*)row_start + (size_t)NN*4); // NE (+16 pad)
    float*  scores    = (float*)((char*)csr + (size_t)(NE+16)*4); // NN

    int* chist = (int*)Bh;   // NB*8*NGRAPH ints (4.096 MB), consumed before agg1

    prep_kernel<<<512 + (FEAT * G1D) / 256, 256, 0, stream>>>(edge, chist, emb, W1, embW);
    scan_graph<<<NB, 256, 0, stream>>>(chist, dinv, row_start);
    mid_kernel<<<512 + (NN * 8) / 1024, 1024, 0, stream>>>(edge, row_start, csr,
                                                           x, embW, dinv, Ah);
    agg1_kernel<<<NB * AGG_PARTS, 1024, 0, stream>>>(Ah, dinv, row_start, csr, b1, W2, Bh);
    agg2_kernel<<<NB * AGG_PARTS, 1024, 0, stream>>>(Bh, dinv, row_start, csr, b2, pool_w, Ah, scores);
    topk_pool_mlp<<<NB, 1024, 0, stream>>>(Ah, scores, dense_W, dense_b, out_W, out_b, outp);
}